// Round 1
// baseline (750.111 us; speedup 1.0000x reference)
//
#include <hip/hip_runtime.h>

constexpr int N_NODES = 100000;
constexpr int N_EDGES = 1600000;
constexpr int DIN = 128, DHID = 256, DOUT = 128;
constexpr int SCAN_BLK = 1024;

// ---------------- degree histogram ----------------
__global__ void hist_kernel(const int* __restrict__ src, const int* __restrict__ dst,
                            int* __restrict__ dout, int* __restrict__ din, int e) {
    for (int i = blockIdx.x * blockDim.x + threadIdx.x; i < e; i += gridDim.x * blockDim.x) {
        atomicAdd(&dout[src[i]], 1);
        atomicAdd(&din[dst[i]], 1);
    }
}

// ---------------- scan (3-phase) for CSR rowstart ----------------
__global__ __launch_bounds__(SCAN_BLK) void scan_sums(const int* __restrict__ cnt,
                                                      int* __restrict__ bsum, int n) {
    __shared__ int s[SCAN_BLK];
    int i = blockIdx.x * SCAN_BLK + threadIdx.x;
    s[threadIdx.x] = (i < n) ? cnt[i] : 0;
    __syncthreads();
    for (int off = SCAN_BLK / 2; off > 0; off >>= 1) {
        if (threadIdx.x < off) s[threadIdx.x] += s[threadIdx.x + off];
        __syncthreads();
    }
    if (threadIdx.x == 0) bsum[blockIdx.x] = s[0];
}

__global__ __launch_bounds__(128) void scan_offsets(const int* __restrict__ bsum,
                                                    int* __restrict__ boff, int nb,
                                                    int* __restrict__ rowstart, int n) {
    __shared__ int s[128];
    int t = threadIdx.x;
    int v = (t < nb) ? bsum[t] : 0;
    s[t] = v;
    __syncthreads();
    for (int off = 1; off < 128; off <<= 1) {
        int add = (t >= off) ? s[t - off] : 0;
        __syncthreads();
        s[t] += add;
        __syncthreads();
    }
    if (t < nb) boff[t] = s[t] - v;  // exclusive
    if (t == 127) rowstart[n] = s[127];  // total == E
}

__global__ __launch_bounds__(SCAN_BLK) void scan_final(const int* __restrict__ cnt,
                                                       const int* __restrict__ boff,
                                                       int* __restrict__ rowstart, int n) {
    __shared__ int s[SCAN_BLK];
    int t = threadIdx.x;
    int i = blockIdx.x * SCAN_BLK + t;
    int v = (i < n) ? cnt[i] : 0;
    s[t] = v;
    __syncthreads();
    for (int off = 1; off < SCAN_BLK; off <<= 1) {
        int add = (t >= off) ? s[t - off] : 0;
        __syncthreads();
        s[t] += add;
        __syncthreads();
    }
    if (i < n) rowstart[i] = boff[blockIdx.x] + s[t] - v;
}

// ---------------- norms (in-place over degree ints) ----------------
__global__ void norms_kernel(const int* __restrict__ dego, const int* __restrict__ degi,
                             float* __restrict__ nsrc, float* __restrict__ ndst, int n) {
    int i = blockIdx.x * blockDim.x + threadIdx.x;
    if (i < n) {
        float go = (float)dego[i];
        float gi = (float)degi[i];
        nsrc[i] = rsqrtf(fmaxf(go, 1.0f));
        ndst[i] = rsqrtf(fmaxf(gi, 1.0f));
    }
}

// ---------------- CSR fill ----------------
__global__ void fill_kernel(const int* __restrict__ src, const int* __restrict__ dst,
                            const int* __restrict__ rowstart, int* __restrict__ cursor,
                            int* __restrict__ csr, int e) {
    for (int i = blockIdx.x * blockDim.x + threadIdx.x; i < e; i += gridDim.x * blockDim.x) {
        int d = dst[i];
        int pos = rowstart[d] + atomicAdd(&cursor[d], 1);
        csr[pos] = src[i];
    }
}

// ---------------- gather-aggregate: one block (128 thr) per dst row ----------------
template <bool SRCSCALE, bool ADDBIAS>
__global__ __launch_bounds__(128) void agg_kernel(const float* __restrict__ X,
                                                  const int* __restrict__ csr,
                                                  const int* __restrict__ rowstart,
                                                  const float* __restrict__ nsrc,
                                                  const float* __restrict__ ndst,
                                                  const float* __restrict__ bias,
                                                  float* __restrict__ out) {
    int d = blockIdx.x;
    int f = threadIdx.x;
    int beg = rowstart[d], end = rowstart[d + 1];
    float acc = 0.0f;
    int k = beg;
    for (; k + 4 <= end; k += 4) {
        int s0 = csr[k], s1 = csr[k + 1], s2 = csr[k + 2], s3 = csr[k + 3];
        float x0 = X[(size_t)s0 * 128 + f];
        float x1 = X[(size_t)s1 * 128 + f];
        float x2 = X[(size_t)s2 * 128 + f];
        float x3 = X[(size_t)s3 * 128 + f];
        if constexpr (SRCSCALE) {
            acc += x0 * nsrc[s0] + x1 * nsrc[s1] + x2 * nsrc[s2] + x3 * nsrc[s3];
        } else {
            acc += x0 + x1 + x2 + x3;
        }
    }
    for (; k < end; ++k) {
        int s = csr[k];
        float x = X[(size_t)s * 128 + f];
        if constexpr (SRCSCALE) acc += x * nsrc[s];
        else acc += x;
    }
    float v = acc * ndst[d];
    if constexpr (ADDBIAS) v += bias[f];
    out[(size_t)d * 128 + f] = v;
}

// ---------------- fp32 GEMM: C[M x NOUT] = A[M x K] @ B[K x NOUT], optional epilogue ----------------
// BM=BN=128, KB=32, 256 threads, 8x8 microtile (split as 2x float4 halves 64 apart)
template <int K, int NOUT, bool EPI_RELU>
__global__ __launch_bounds__(256) void gemm_kernel(const float* __restrict__ A,
                                                   const float* __restrict__ B,
                                                   const float* __restrict__ bias,
                                                   const float* __restrict__ rowscale,
                                                   float* __restrict__ C, int M) {
    constexpr int BM = 128, BN = 128, KB = 32;
    __shared__ float AsT[KB][132];  // [k][row], padded
    __shared__ float Bs[KB][132];   // [k][col], padded
    const int row0 = blockIdx.x * BM;
    const int col0 = blockIdx.y * BN;
    const int t = threadIdx.x;
    const int tx = t & 15, ty = t >> 4;

    float acc[8][8];
#pragma unroll
    for (int i = 0; i < 8; i++)
#pragma unroll
        for (int j = 0; j < 8; j++) acc[i][j] = 0.0f;

    for (int kb = 0; kb < K; kb += KB) {
        // load A tile (128 rows x 32 k), transposed into LDS
#pragma unroll
        for (int i = 0; i < 4; i++) {
            int idx = i * 256 + t;   // 0..1023
            int r = idx >> 3;        // row in tile (8 float4 per row)
            int c4 = idx & 7;
            int grow = row0 + r;
            float4 v = make_float4(0.f, 0.f, 0.f, 0.f);
            if (grow < M) v = *reinterpret_cast<const float4*>(&A[(size_t)grow * K + kb + c4 * 4]);
            AsT[c4 * 4 + 0][r] = v.x;
            AsT[c4 * 4 + 1][r] = v.y;
            AsT[c4 * 4 + 2][r] = v.z;
            AsT[c4 * 4 + 3][r] = v.w;
        }
        // load B tile (32 k x 128 cols)
#pragma unroll
        for (int i = 0; i < 4; i++) {
            int idx = i * 256 + t;
            int r = idx >> 5;  // 32 float4 per row
            int c4 = idx & 31;
            float4 v = *reinterpret_cast<const float4*>(&B[(size_t)(kb + r) * NOUT + col0 + c4 * 4]);
            *reinterpret_cast<float4*>(&Bs[r][c4 * 4]) = v;
        }
        __syncthreads();
#pragma unroll
        for (int kk = 0; kk < KB; kk++) {
            float4 a0 = *reinterpret_cast<const float4*>(&AsT[kk][ty * 4]);
            float4 a1 = *reinterpret_cast<const float4*>(&AsT[kk][ty * 4 + 64]);
            float4 b0 = *reinterpret_cast<const float4*>(&Bs[kk][tx * 4]);
            float4 b1 = *reinterpret_cast<const float4*>(&Bs[kk][tx * 4 + 64]);
            float a[8] = {a0.x, a0.y, a0.z, a0.w, a1.x, a1.y, a1.z, a1.w};
            float b[8] = {b0.x, b0.y, b0.z, b0.w, b1.x, b1.y, b1.z, b1.w};
#pragma unroll
            for (int ri = 0; ri < 8; ri++)
#pragma unroll
                for (int ci = 0; ci < 8; ci++) acc[ri][ci] += a[ri] * b[ci];
        }
        __syncthreads();
    }

    // epilogue + store
#pragma unroll
    for (int rh = 0; rh < 2; rh++) {
#pragma unroll
        for (int i = 0; i < 4; i++) {
            int ri = rh * 4 + i;
            int r = row0 + ty * 4 + i + rh * 64;
            if (r >= M) continue;
            float rs = 1.0f;
            if (EPI_RELU) rs = rowscale[r];
#pragma unroll
            for (int ch = 0; ch < 2; ch++) {
                int c = col0 + tx * 4 + ch * 64;
                float4 v = make_float4(acc[ri][ch * 4 + 0], acc[ri][ch * 4 + 1],
                                       acc[ri][ch * 4 + 2], acc[ri][ch * 4 + 3]);
                if (EPI_RELU) {
                    v.x = fmaxf(v.x + bias[c + 0], 0.0f) * rs;
                    v.y = fmaxf(v.y + bias[c + 1], 0.0f) * rs;
                    v.z = fmaxf(v.z + bias[c + 2], 0.0f) * rs;
                    v.w = fmaxf(v.w + bias[c + 3], 0.0f) * rs;
                }
                *reinterpret_cast<float4*>(&C[(size_t)r * NOUT + c]) = v;
            }
        }
    }
}

extern "C" void kernel_launch(void* const* d_in, const int* in_sizes, int n_in,
                              void* d_out, int out_size, void* d_ws, size_t ws_size,
                              hipStream_t stream) {
    const float* x  = (const float*)d_in[0];
    const int*   src = (const int*)d_in[1];
    const int*   dst = (const int*)d_in[2];
    const float* W1 = (const float*)d_in[3];
    const float* b1 = (const float*)d_in[4];
    const float* W2 = (const float*)d_in[5];
    const float* b2 = (const float*)d_in[6];
    float* out = (float*)d_out;

    const int N = N_NODES, E = N_EDGES;

    size_t off = 0;
    auto carve = [&](size_t bytes) -> void* {
        void* p = (char*)d_ws + off;
        off += (bytes + 255) & ~(size_t)255;
        return p;
    };
    int* deg_out  = (int*)carve((size_t)N * 4);
    int* deg_in   = (int*)carve((size_t)N * 4);
    int* cursor   = (int*)carve((size_t)N * 4);
    int* rowstart = (int*)carve((size_t)(N + 1) * 4);
    int* bsum     = (int*)carve(128 * 4);
    int* boff     = (int*)carve(128 * 4);
    int* csr      = (int*)carve((size_t)E * 4);
    float* agg1   = (float*)carve((size_t)N * DIN * 4);   // reused as t after GEMM2
    float* h1s    = (float*)carve((size_t)N * DHID * 4);
    float* nsrc = (float*)deg_out;  // overwritten in place by norms_kernel
    float* ndst = (float*)deg_in;

    // zero deg_out, deg_in, cursor (contiguous carve region)
    size_t zbytes = (char*)rowstart - (char*)deg_out;
    hipMemsetAsync(deg_out, 0, zbytes, stream);

    hist_kernel<<<2048, 256, 0, stream>>>(src, dst, deg_out, deg_in, E);

    const int nb = (N + SCAN_BLK - 1) / SCAN_BLK;  // 98
    scan_sums<<<nb, SCAN_BLK, 0, stream>>>(deg_in, bsum, N);
    scan_offsets<<<1, 128, 0, stream>>>(bsum, boff, nb, rowstart, N);
    scan_final<<<nb, SCAN_BLK, 0, stream>>>(deg_in, boff, rowstart, N);

    norms_kernel<<<(N + 255) / 256, 256, 0, stream>>>(deg_out, deg_in, nsrc, ndst, N);

    fill_kernel<<<2048, 256, 0, stream>>>(src, dst, rowstart, cursor, csr, E);

    // layer 1 aggregation: agg1 = norm_dst * segsum((x*norm_src)[src])
    agg_kernel<true, false><<<N, 128, 0, stream>>>(x, csr, rowstart, nsrc, ndst, nullptr, agg1);

    // GEMM1: h1s = relu(agg1 @ W1 + b1) * norm_src
    dim3 g1((N + 127) / 128, DHID / 128);
    gemm_kernel<DIN, DHID, true><<<g1, 256, 0, stream>>>(agg1, W1, b1, nsrc, h1s, N);

    // GEMM2: t = h1s @ W2   (t overwrites agg1 buffer)
    float* tbuf = agg1;
    dim3 g2((N + 127) / 128, DOUT / 128);
    gemm_kernel<DHID, DOUT, false><<<g2, 256, 0, stream>>>(h1s, W2, nullptr, nullptr, tbuf, N);

    // layer 2 aggregation: out = norm_dst * segsum(t[src]) + b2
    agg_kernel<false, true><<<N, 128, 0, stream>>>(tbuf, csr, rowstart, nullptr, ndst, b2, out);
}

// Round 2
// 612.426 us; speedup vs baseline: 1.2248x; 1.2248x over previous
//
#include <hip/hip_runtime.h>

constexpr int N_NODES = 100000;
constexpr int N_EDGES = 1600000;
constexpr int DIN = 128, DHID = 256, DOUT = 128;
constexpr int SCAN_BLK = 1024;

typedef __bf16 bf16x8 __attribute__((ext_vector_type(8)));
typedef float f32x4 __attribute__((ext_vector_type(4)));

static __device__ __forceinline__ ushort f2bf(float f) {
    uint u = __float_as_uint(f);
    uint r = (u + 0x7FFFu + ((u >> 16) & 1u)) >> 16;
    return (ushort)r;
}
static __device__ __forceinline__ float bf2f(ushort h) {
    return __uint_as_float(((uint)h) << 16);
}

// ---------------- degree histogram ----------------
__global__ void hist_kernel(const int* __restrict__ src, const int* __restrict__ dst,
                            int* __restrict__ dout, int* __restrict__ din, int e) {
    for (int i = blockIdx.x * blockDim.x + threadIdx.x; i < e; i += gridDim.x * blockDim.x) {
        atomicAdd(&dout[src[i]], 1);
        atomicAdd(&din[dst[i]], 1);
    }
}

// ---------------- scan (3-phase) for CSR rowstart ----------------
__global__ __launch_bounds__(SCAN_BLK) void scan_sums(const int* __restrict__ cnt,
                                                      int* __restrict__ bsum, int n) {
    __shared__ int s[SCAN_BLK];
    int i = blockIdx.x * SCAN_BLK + threadIdx.x;
    s[threadIdx.x] = (i < n) ? cnt[i] : 0;
    __syncthreads();
    for (int off = SCAN_BLK / 2; off > 0; off >>= 1) {
        if (threadIdx.x < off) s[threadIdx.x] += s[threadIdx.x + off];
        __syncthreads();
    }
    if (threadIdx.x == 0) bsum[blockIdx.x] = s[0];
}

__global__ __launch_bounds__(128) void scan_offsets(const int* __restrict__ bsum,
                                                    int* __restrict__ boff, int nb,
                                                    int* __restrict__ rowstart, int n) {
    __shared__ int s[128];
    int t = threadIdx.x;
    int v = (t < nb) ? bsum[t] : 0;
    s[t] = v;
    __syncthreads();
    for (int off = 1; off < 128; off <<= 1) {
        int add = (t >= off) ? s[t - off] : 0;
        __syncthreads();
        s[t] += add;
        __syncthreads();
    }
    if (t < nb) boff[t] = s[t] - v;      // exclusive
    if (t == 127) rowstart[n] = s[127];  // total == E
}

__global__ __launch_bounds__(SCAN_BLK) void scan_final(const int* __restrict__ cnt,
                                                       const int* __restrict__ boff,
                                                       int* __restrict__ rowstart, int n) {
    __shared__ int s[SCAN_BLK];
    int t = threadIdx.x;
    int i = blockIdx.x * SCAN_BLK + t;
    int v = (i < n) ? cnt[i] : 0;
    s[t] = v;
    __syncthreads();
    for (int off = 1; off < SCAN_BLK; off <<= 1) {
        int add = (t >= off) ? s[t - off] : 0;
        __syncthreads();
        s[t] += add;
        __syncthreads();
    }
    if (i < n) rowstart[i] = boff[blockIdx.x] + s[t] - v;
}

// ---------------- norms (in-place over degree ints) ----------------
__global__ void norms_kernel(const int* __restrict__ dego, const int* __restrict__ degi,
                             float* __restrict__ nsrc, float* __restrict__ ndst, int n) {
    int i = blockIdx.x * blockDim.x + threadIdx.x;
    if (i < n) {
        float go = (float)dego[i];
        float gi = (float)degi[i];
        nsrc[i] = rsqrtf(fmaxf(go, 1.0f));
        ndst[i] = rsqrtf(fmaxf(gi, 1.0f));
    }
}

// ---------------- CSR fill ----------------
__global__ void fill_kernel(const int* __restrict__ src, const int* __restrict__ dst,
                            const int* __restrict__ rowstart, int* __restrict__ cursor,
                            int* __restrict__ csr, int e) {
    for (int i = blockIdx.x * blockDim.x + threadIdx.x; i < e; i += gridDim.x * blockDim.x) {
        int d = dst[i];
        int pos = rowstart[d] + atomicAdd(&cursor[d], 1);
        csr[pos] = src[i];
    }
}

// ---------------- W pre-convert: fp32 [K][N] -> transposed bf16 hi/lo [N][K] ----------------
__global__ void wconv_kernel(const float* __restrict__ W, ushort* __restrict__ hi,
                             ushort* __restrict__ lo, int K, int N) {
    int i = blockIdx.x * blockDim.x + threadIdx.x;
    if (i < K * N) {
        int k = i / N;
        int n = i - k * N;
        float w = W[i];
        ushort h = f2bf(w);
        ushort l = f2bf(w - bf2f(h));
        hi[(size_t)n * K + k] = h;
        lo[(size_t)n * K + k] = l;
    }
}

// ---------------- gather-aggregate: 8 dst rows / block, float4 per lane-of-32 ----------------
template <bool SRCSCALE, bool ADDBIAS>
__global__ __launch_bounds__(256) void agg4_kernel(const float* __restrict__ X,
                                                   const int* __restrict__ csr,
                                                   const int* __restrict__ rowstart,
                                                   const float* __restrict__ nsrc,
                                                   const float* __restrict__ ndst,
                                                   const float* __restrict__ bias,
                                                   float* __restrict__ out, int n) {
    int rl = threadIdx.x >> 5;     // 0..7
    int lane = threadIdx.x & 31;   // feature group: floats [lane*4, lane*4+4)
    int d = blockIdx.x * 8 + rl;
    if (d >= n) return;
    int beg = rowstart[d], end = rowstart[d + 1];
    float ax = 0.f, ay = 0.f, az = 0.f, aw = 0.f;
    int fo = lane * 4;
    int k = beg;
    for (; k + 4 <= end; k += 4) {
        int s0 = csr[k], s1 = csr[k + 1], s2 = csr[k + 2], s3 = csr[k + 3];
        float4 x0 = *(const float4*)&X[(size_t)s0 * 128 + fo];
        float4 x1 = *(const float4*)&X[(size_t)s1 * 128 + fo];
        float4 x2 = *(const float4*)&X[(size_t)s2 * 128 + fo];
        float4 x3 = *(const float4*)&X[(size_t)s3 * 128 + fo];
        if constexpr (SRCSCALE) {
            float w0 = nsrc[s0], w1 = nsrc[s1], w2 = nsrc[s2], w3 = nsrc[s3];
            ax += x0.x * w0 + x1.x * w1 + x2.x * w2 + x3.x * w3;
            ay += x0.y * w0 + x1.y * w1 + x2.y * w2 + x3.y * w3;
            az += x0.z * w0 + x1.z * w1 + x2.z * w2 + x3.z * w3;
            aw += x0.w * w0 + x1.w * w1 + x2.w * w2 + x3.w * w3;
        } else {
            ax += x0.x + x1.x + x2.x + x3.x;
            ay += x0.y + x1.y + x2.y + x3.y;
            az += x0.z + x1.z + x2.z + x3.z;
            aw += x0.w + x1.w + x2.w + x3.w;
        }
    }
    for (; k < end; ++k) {
        int s = csr[k];
        float4 x = *(const float4*)&X[(size_t)s * 128 + fo];
        float w = SRCSCALE ? nsrc[s] : 1.0f;
        ax += x.x * w;
        ay += x.y * w;
        az += x.z * w;
        aw += x.w * w;
    }
    float nd = ndst[d];
    float4 v;
    v.x = ax * nd;
    v.y = ay * nd;
    v.z = az * nd;
    v.w = aw * nd;
    if constexpr (ADDBIAS) {
        const float4 b = *(const float4*)&bias[fo];
        v.x += b.x;
        v.y += b.y;
        v.z += b.z;
        v.w += b.w;
    }
    *(float4*)&out[(size_t)d * 128 + fo] = v;
}

// ---------------- split-bf16 MFMA GEMM: C[M x NOUT] = A[M x K] @ B[K x NOUT] ----------------
// BM=BN=128, KB=32, 256 threads = 4 waves (2x2), each wave 64x64 = 4x4 frags of 16x16.
// fp32 A split on the fly into bf16 hi/lo during LDS staging; B pre-split+transposed.
template <int K, int NOUT, bool EPI_RELU>
__global__ __launch_bounds__(256) void mgemm_kernel(const float* __restrict__ A,
                                                    const ushort* __restrict__ BtHi,
                                                    const ushort* __restrict__ BtLo,
                                                    const float* __restrict__ bias,
                                                    const float* __restrict__ rowscale,
                                                    float* __restrict__ C, int M) {
    constexpr int BM = 128, BN = 128, KB = 32, LDT = 40;  // pad 32->40 ushorts (80B stride)
    __shared__ ushort AsHi[BM][LDT], AsLo[BM][LDT], BsHi[BN][LDT], BsLo[BN][LDT];
    const int row0 = blockIdx.x * BM, col0 = blockIdx.y * BN;
    const int t = threadIdx.x;
    const int wid = t >> 6, lane = t & 63;
    const int wr = wid >> 1, wc = wid & 1;
    const int l16 = lane & 15, lk = lane >> 4;

    f32x4 acc[4][4];
#pragma unroll
    for (int i = 0; i < 4; i++)
#pragma unroll
        for (int j = 0; j < 4; j++) acc[i][j] = (f32x4){0.f, 0.f, 0.f, 0.f};

    for (int kb = 0; kb < K; kb += KB) {
        // stage A: 128 rows x 32 k fp32, convert to hi/lo bf16
#pragma unroll
        for (int i = 0; i < 4; i++) {
            int idx = i * 256 + t;          // 0..1023 float4-pieces
            int r = idx >> 3, c4 = idx & 7; // row, k-quad
            int gr = row0 + r;
            float4 v = make_float4(0.f, 0.f, 0.f, 0.f);
            if (gr < M) v = *(const float4*)&A[(size_t)gr * K + kb + c4 * 4];
            ushort h0 = f2bf(v.x), h1 = f2bf(v.y), h2 = f2bf(v.z), h3 = f2bf(v.w);
            ushort l0 = f2bf(v.x - bf2f(h0)), l1 = f2bf(v.y - bf2f(h1));
            ushort l2 = f2bf(v.z - bf2f(h2)), l3 = f2bf(v.w - bf2f(h3));
            ushort4 hv = {h0, h1, h2, h3};
            ushort4 lv = {l0, l1, l2, l3};
            *(ushort4*)&AsHi[r][c4 * 4] = hv;
            *(ushort4*)&AsLo[r][c4 * 4] = lv;
        }
        // stage B: from pre-transposed bf16 [NOUT][K]
#pragma unroll
        for (int i = 0; i < 2; i++) {
            int idx = i * 256 + t;          // 0..511 ushort8-pieces
            int r = idx >> 2, s = idx & 3;  // row, k-octet
            *(uint4*)&BsHi[r][s * 8] = *(const uint4*)&BtHi[(size_t)(col0 + r) * K + kb + s * 8];
            *(uint4*)&BsLo[r][s * 8] = *(const uint4*)&BtLo[(size_t)(col0 + r) * K + kb + s * 8];
        }
        __syncthreads();

        bf16x8 ah[4], al[4], bh[4], bl[4];
#pragma unroll
        for (int i = 0; i < 4; i++) {
            int m = wr * 64 + i * 16 + l16;
            ah[i] = *(const bf16x8*)&AsHi[m][lk * 8];
            al[i] = *(const bf16x8*)&AsLo[m][lk * 8];
            int nn = wc * 64 + i * 16 + l16;
            bh[i] = *(const bf16x8*)&BsHi[nn][lk * 8];
            bl[i] = *(const bf16x8*)&BsLo[nn][lk * 8];
        }
#pragma unroll
        for (int i = 0; i < 4; i++)
#pragma unroll
            for (int j = 0; j < 4; j++) {
                acc[i][j] = __builtin_amdgcn_mfma_f32_16x16x32_bf16(ah[i], bh[j], acc[i][j], 0, 0, 0);
                acc[i][j] = __builtin_amdgcn_mfma_f32_16x16x32_bf16(ah[i], bl[j], acc[i][j], 0, 0, 0);
                acc[i][j] = __builtin_amdgcn_mfma_f32_16x16x32_bf16(al[i], bh[j], acc[i][j], 0, 0, 0);
            }
        __syncthreads();
    }

    // epilogue: C/D layout col=lane&15, row=(lane>>4)*4+q  [m89/m91-verified]
#pragma unroll
    for (int i = 0; i < 4; i++) {
#pragma unroll
        for (int j = 0; j < 4; j++) {
#pragma unroll
            for (int q = 0; q < 4; q++) {
                int r = row0 + wr * 64 + i * 16 + lk * 4 + q;
                int c = col0 + wc * 64 + j * 16 + l16;
                if (r < M) {
                    float v = acc[i][j][q];
                    if constexpr (EPI_RELU) v = fmaxf(v + bias[c], 0.f) * rowscale[r];
                    C[(size_t)r * NOUT + c] = v;
                }
            }
        }
    }
}

extern "C" void kernel_launch(void* const* d_in, const int* in_sizes, int n_in,
                              void* d_out, int out_size, void* d_ws, size_t ws_size,
                              hipStream_t stream) {
    const float* x  = (const float*)d_in[0];
    const int*   src = (const int*)d_in[1];
    const int*   dst = (const int*)d_in[2];
    const float* W1 = (const float*)d_in[3];
    const float* b1 = (const float*)d_in[4];
    const float* W2 = (const float*)d_in[5];
    const float* b2 = (const float*)d_in[6];
    float* out = (float*)d_out;

    const int N = N_NODES, E = N_EDGES;

    size_t off = 0;
    auto carve = [&](size_t bytes) -> void* {
        void* p = (char*)d_ws + off;
        off += (bytes + 255) & ~(size_t)255;
        return p;
    };
    int* deg_out  = (int*)carve((size_t)N * 4);
    int* deg_in   = (int*)carve((size_t)N * 4);
    int* cursor   = (int*)carve((size_t)N * 4);  // also reused for Wt after fill
    int* rowstart = (int*)carve((size_t)(N + 1) * 4);
    int* bsum     = (int*)carve(128 * 4);
    int* boff     = (int*)carve(128 * 4);
    int* csr      = (int*)carve((size_t)E * 4);
    float* agg1   = (float*)carve((size_t)N * DIN * 4);   // reused as t after GEMM2
    float* h1s    = (float*)carve((size_t)N * DHID * 4);
    float* nsrc = (float*)deg_out;  // overwritten in place by norms_kernel
    float* ndst = (float*)deg_in;

    // Wt buffers alias the cursor region (dead after fill_kernel): 4 x 64KB = 256KB <= 400KB
    ushort* Wt1Hi = (ushort*)((char*)cursor + 0);
    ushort* Wt1Lo = (ushort*)((char*)cursor + 65536);
    ushort* Wt2Hi = (ushort*)((char*)cursor + 131072);
    ushort* Wt2Lo = (ushort*)((char*)cursor + 196608);

    // zero deg_out, deg_in, cursor (contiguous carve region)
    size_t zbytes = (char*)rowstart - (char*)deg_out;
    hipMemsetAsync(deg_out, 0, zbytes, stream);

    hist_kernel<<<2048, 256, 0, stream>>>(src, dst, deg_out, deg_in, E);

    const int nb = (N + SCAN_BLK - 1) / SCAN_BLK;  // 98
    scan_sums<<<nb, SCAN_BLK, 0, stream>>>(deg_in, bsum, N);
    scan_offsets<<<1, 128, 0, stream>>>(bsum, boff, nb, rowstart, N);
    scan_final<<<nb, SCAN_BLK, 0, stream>>>(deg_in, boff, rowstart, N);

    norms_kernel<<<(N + 255) / 256, 256, 0, stream>>>(deg_out, deg_in, nsrc, ndst, N);

    fill_kernel<<<2048, 256, 0, stream>>>(src, dst, rowstart, cursor, csr, E);

    // convert weights (after fill: cursor region is dead now)
    wconv_kernel<<<(DIN * DHID + 255) / 256, 256, 0, stream>>>(W1, Wt1Hi, Wt1Lo, DIN, DHID);
    wconv_kernel<<<(DHID * DOUT + 255) / 256, 256, 0, stream>>>(W2, Wt2Hi, Wt2Lo, DHID, DOUT);

    // layer 1 aggregation: agg1 = norm_dst * segsum((x*norm_src)[src])
    agg4_kernel<true, false><<<(N + 7) / 8, 256, 0, stream>>>(x, csr, rowstart, nsrc, ndst, nullptr, agg1, N);

    // GEMM1: h1s = relu(agg1 @ W1 + b1) * norm_src
    dim3 g1((N + 127) / 128, DHID / 128);
    mgemm_kernel<DIN, DHID, true><<<g1, 256, 0, stream>>>(agg1, Wt1Hi, Wt1Lo, b1, nsrc, h1s, N);

    // GEMM2: t = h1s @ W2   (t overwrites agg1 buffer)
    float* tbuf = agg1;
    dim3 g2((N + 127) / 128, DOUT / 128);
    mgemm_kernel<DHID, DOUT, false><<<g2, 256, 0, stream>>>(h1s, Wt2Hi, Wt2Lo, nullptr, nullptr, tbuf, N);

    // layer 2 aggregation: out = norm_dst * segsum(t[src]) + b2
    agg4_kernel<false, true><<<(N + 7) / 8, 256, 0, stream>>>(tbuf, csr, rowstart, nullptr, ndst, b2, out, N);
}

// Round 3
// 426.514 us; speedup vs baseline: 1.7587x; 1.4359x over previous
//
#include <hip/hip_runtime.h>

constexpr int N_NODES = 100000;
constexpr int N_EDGES = 1600000;
constexpr int DIN = 128, DHID = 256, DOUT = 128;

constexpr int NB = 256;    // buckets
constexpr int BR = 391;    // node range per bucket (256*391 = 100096 >= N)
constexpr int CAP = 8192;  // per-bucket capacity (mean 6250, 24 sigma slack)
constexpr int NBLK1 = 512;
constexpr int CHUNK = (N_EDGES + NBLK1 - 1) / NBLK1;  // 3125

typedef __bf16 bf16x8 __attribute__((ext_vector_type(8)));
typedef float f32x4 __attribute__((ext_vector_type(4)));

static __device__ __forceinline__ ushort f2bf(float f) {
    uint u = __float_as_uint(f);
    uint r = (u + 0x7FFFu + ((u >> 16) & 1u)) >> 16;
    return (ushort)r;
}
static __device__ __forceinline__ float bf2f(ushort h) {
    return __uint_as_float(((uint)h) << 16);
}

// ---------------- pass 1: partition edges into 256 buckets by dst/BR and src/BR ----------------
__global__ __launch_bounds__(256) void part_kernel(const int* __restrict__ src,
                                                   const int* __restrict__ dst,
                                                   int* __restrict__ curA, int* __restrict__ curB,
                                                   uint2* __restrict__ ppair,
                                                   int* __restrict__ psv, int e) {
    __shared__ uint2 estage[CHUNK];
    __shared__ int hA[NB], hB[NB], rA[NB], rB[NB], cA[NB], cB[NB];
    const int t = threadIdx.x;
    const int b0 = blockIdx.x * CHUNK;
    const int cnt = min(e - b0, CHUNK);
    hA[t] = 0; hB[t] = 0; cA[t] = 0; cB[t] = 0;
    __syncthreads();
    for (int i = t; i < cnt; i += 256) {
        int s = src[b0 + i], d = dst[b0 + i];
        estage[i] = make_uint2((uint)d, (uint)s);
        atomicAdd(&hA[d / BR], 1);
        atomicAdd(&hB[s / BR], 1);
    }
    __syncthreads();
    rA[t] = atomicAdd(&curA[t], hA[t]);  // global reservation (256/block)
    rB[t] = atomicAdd(&curB[t], hB[t]);
    __syncthreads();
    for (int i = t; i < cnt; i += 256) {
        uint2 ed = estage[i];
        int bd = (int)ed.x / BR;
        int bs = (int)ed.y / BR;
        int p = rA[bd] + atomicAdd(&cA[bd], 1);
        if (p < CAP) ppair[(size_t)bd * CAP + p] = ed;
        int q = rB[bs] + atomicAdd(&cB[bs], 1);
        if (q < CAP) psv[(size_t)bs * CAP + q] = (int)ed.y;
    }
}

// ---------------- exclusive scan over 256 bucket counts ----------------
__global__ __launch_bounds__(256) void bscan_kernel(const int* __restrict__ curA,
                                                    int* __restrict__ bstart,
                                                    int* __restrict__ rowstart, int n, int e) {
    __shared__ int s[256];
    int t = threadIdx.x;
    int v = curA[t];
    s[t] = v;
    __syncthreads();
    for (int off = 1; off < 256; off <<= 1) {
        int add = (t >= off) ? s[t - off] : 0;
        __syncthreads();
        s[t] += add;
        __syncthreads();
    }
    bstart[t] = s[t] - v;  // exclusive
    if (t == 255) {
        bstart[256] = s[255];
        rowstart[n] = e;
    }
}

// ---------------- pass 2a: per-bucket CSR build + rowstart + ndst (LDS atomics only) ---------
__global__ __launch_bounds__(512) void csr_kernel(const int* __restrict__ curA,
                                                  const int* __restrict__ bstart,
                                                  const uint2* __restrict__ ppair,
                                                  int* __restrict__ csr,
                                                  int* __restrict__ rowstart,
                                                  float* __restrict__ ndst, int n) {
    __shared__ ushort dloc[CAP];   // 16KB
    __shared__ uint sloc[CAP];     // 32KB
    __shared__ int hist[512], sc[512], exc[512], cur[512];
    const int t = threadIdx.x;
    const int b = blockIdx.x;
    const int first = b * BR;
    const int nr = min(BR, n - first);
    const int cnt = min(curA[b], CAP);
    const size_t base = (size_t)b * CAP;
    const int bst = bstart[b];
    hist[t] = 0;
    cur[t] = 0;
    __syncthreads();
    for (int i = t; i < cnt; i += 512) {
        uint2 ed = ppair[base + i];
        int dl = (int)ed.x - first;
        dloc[i] = (ushort)dl;
        sloc[i] = ed.y;
        atomicAdd(&hist[dl], 1);
    }
    __syncthreads();
    int h = hist[t];
    sc[t] = h;
    __syncthreads();
    for (int off = 1; off < 512; off <<= 1) {
        int add = (t >= off) ? sc[t - off] : 0;
        __syncthreads();
        sc[t] += add;
        __syncthreads();
    }
    exc[t] = sc[t] - h;
    if (t < nr) {
        rowstart[first + t] = bst + exc[t];
        ndst[first + t] = rsqrtf(fmaxf((float)h, 1.0f));
    }
    __syncthreads();
    for (int i = t; i < cnt; i += 512) {
        int dl = dloc[i];
        int p = exc[dl] + atomicAdd(&cur[dl], 1);
        csr[bst + p] = (int)sloc[i];
    }
}

// ---------------- pass 2b: per-bucket out-degree -> nsrc (LDS atomics only) ----------------
__global__ __launch_bounds__(512) void nsrc_kernel(const int* __restrict__ curB,
                                                   const int* __restrict__ psv,
                                                   float* __restrict__ nsrc, int n) {
    __shared__ int hist[512];
    const int t = threadIdx.x;
    const int b = blockIdx.x;
    const int first = b * BR;
    const int nr = min(BR, n - first);
    const int cnt = min(curB[b], CAP);
    const size_t base = (size_t)b * CAP;
    hist[t] = 0;
    __syncthreads();
    for (int i = t; i < cnt; i += 512) atomicAdd(&hist[psv[base + i] - first], 1);
    __syncthreads();
    if (t < nr) nsrc[first + t] = rsqrtf(fmaxf((float)hist[t], 1.0f));
}

// ---------------- W pre-convert: fp32 [K][N] -> transposed bf16 hi/lo [N][K] ----------------
__global__ void wconv_kernel(const float* __restrict__ W, ushort* __restrict__ hi,
                             ushort* __restrict__ lo, int K, int N) {
    int i = blockIdx.x * blockDim.x + threadIdx.x;
    if (i < K * N) {
        int k = i / N;
        int n = i - k * N;
        float w = W[i];
        ushort h = f2bf(w);
        ushort l = f2bf(w - bf2f(h));
        hi[(size_t)n * K + k] = h;
        lo[(size_t)n * K + k] = l;
    }
}

// ---------------- gather-aggregate: 8 dst rows / block, float4 per lane-of-32 ----------------
template <bool SRCSCALE, bool ADDBIAS>
__global__ __launch_bounds__(256) void agg4_kernel(const float* __restrict__ X,
                                                   const int* __restrict__ csr,
                                                   const int* __restrict__ rowstart,
                                                   const float* __restrict__ nsrc,
                                                   const float* __restrict__ ndst,
                                                   const float* __restrict__ bias,
                                                   float* __restrict__ out, int n) {
    int rl = threadIdx.x >> 5;    // 0..7
    int lane = threadIdx.x & 31;  // feature group: floats [lane*4, lane*4+4)
    int d = blockIdx.x * 8 + rl;
    if (d >= n) return;
    int beg = rowstart[d], end = rowstart[d + 1];
    float ax = 0.f, ay = 0.f, az = 0.f, aw = 0.f;
    int fo = lane * 4;
    int k = beg;
    for (; k + 4 <= end; k += 4) {
        int s0 = csr[k], s1 = csr[k + 1], s2 = csr[k + 2], s3 = csr[k + 3];
        float4 x0 = *(const float4*)&X[(size_t)s0 * 128 + fo];
        float4 x1 = *(const float4*)&X[(size_t)s1 * 128 + fo];
        float4 x2 = *(const float4*)&X[(size_t)s2 * 128 + fo];
        float4 x3 = *(const float4*)&X[(size_t)s3 * 128 + fo];
        if constexpr (SRCSCALE) {
            float w0 = nsrc[s0], w1 = nsrc[s1], w2 = nsrc[s2], w3 = nsrc[s3];
            ax += x0.x * w0 + x1.x * w1 + x2.x * w2 + x3.x * w3;
            ay += x0.y * w0 + x1.y * w1 + x2.y * w2 + x3.y * w3;
            az += x0.z * w0 + x1.z * w1 + x2.z * w2 + x3.z * w3;
            aw += x0.w * w0 + x1.w * w1 + x2.w * w2 + x3.w * w3;
        } else {
            ax += x0.x + x1.x + x2.x + x3.x;
            ay += x0.y + x1.y + x2.y + x3.y;
            az += x0.z + x1.z + x2.z + x3.z;
            aw += x0.w + x1.w + x2.w + x3.w;
        }
    }
    for (; k < end; ++k) {
        int s = csr[k];
        float4 x = *(const float4*)&X[(size_t)s * 128 + fo];
        float w = SRCSCALE ? nsrc[s] : 1.0f;
        ax += x.x * w;
        ay += x.y * w;
        az += x.z * w;
        aw += x.w * w;
    }
    float nd = ndst[d];
    float4 v;
    v.x = ax * nd;
    v.y = ay * nd;
    v.z = az * nd;
    v.w = aw * nd;
    if constexpr (ADDBIAS) {
        const float4 b = *(const float4*)&bias[fo];
        v.x += b.x;
        v.y += b.y;
        v.z += b.z;
        v.w += b.w;
    }
    *(float4*)&out[(size_t)d * 128 + fo] = v;
}

// ---------------- split-bf16 MFMA GEMM: C[M x NOUT] = A[M x K] @ B[K x NOUT] ----------------
template <int K, int NOUT, bool EPI_RELU>
__global__ __launch_bounds__(256) void mgemm_kernel(const float* __restrict__ A,
                                                    const ushort* __restrict__ BtHi,
                                                    const ushort* __restrict__ BtLo,
                                                    const float* __restrict__ bias,
                                                    const float* __restrict__ rowscale,
                                                    float* __restrict__ C, int M) {
    constexpr int BM = 128, BN = 128, KB = 32, LDT = 40;  // pad 32->40 ushorts (80B stride)
    __shared__ ushort AsHi[BM][LDT], AsLo[BM][LDT], BsHi[BN][LDT], BsLo[BN][LDT];
    const int row0 = blockIdx.x * BM, col0 = blockIdx.y * BN;
    const int t = threadIdx.x;
    const int wid = t >> 6, lane = t & 63;
    const int wr = wid >> 1, wc = wid & 1;
    const int l16 = lane & 15, lk = lane >> 4;

    f32x4 acc[4][4];
#pragma unroll
    for (int i = 0; i < 4; i++)
#pragma unroll
        for (int j = 0; j < 4; j++) acc[i][j] = (f32x4){0.f, 0.f, 0.f, 0.f};

    for (int kb = 0; kb < K; kb += KB) {
#pragma unroll
        for (int i = 0; i < 4; i++) {
            int idx = i * 256 + t;
            int r = idx >> 3, c4 = idx & 7;
            int gr = row0 + r;
            float4 v = make_float4(0.f, 0.f, 0.f, 0.f);
            if (gr < M) v = *(const float4*)&A[(size_t)gr * K + kb + c4 * 4];
            ushort h0 = f2bf(v.x), h1 = f2bf(v.y), h2 = f2bf(v.z), h3 = f2bf(v.w);
            ushort l0 = f2bf(v.x - bf2f(h0)), l1 = f2bf(v.y - bf2f(h1));
            ushort l2 = f2bf(v.z - bf2f(h2)), l3 = f2bf(v.w - bf2f(h3));
            ushort4 hv = {h0, h1, h2, h3};
            ushort4 lv = {l0, l1, l2, l3};
            *(ushort4*)&AsHi[r][c4 * 4] = hv;
            *(ushort4*)&AsLo[r][c4 * 4] = lv;
        }
#pragma unroll
        for (int i = 0; i < 2; i++) {
            int idx = i * 256 + t;
            int r = idx >> 2, s = idx & 3;
            *(uint4*)&BsHi[r][s * 8] = *(const uint4*)&BtHi[(size_t)(col0 + r) * K + kb + s * 8];
            *(uint4*)&BsLo[r][s * 8] = *(const uint4*)&BtLo[(size_t)(col0 + r) * K + kb + s * 8];
        }
        __syncthreads();

        bf16x8 ah[4], al[4], bh[4], bl[4];
#pragma unroll
        for (int i = 0; i < 4; i++) {
            int m = wr * 64 + i * 16 + l16;
            ah[i] = *(const bf16x8*)&AsHi[m][lk * 8];
            al[i] = *(const bf16x8*)&AsLo[m][lk * 8];
            int nn = wc * 64 + i * 16 + l16;
            bh[i] = *(const bf16x8*)&BsHi[nn][lk * 8];
            bl[i] = *(const bf16x8*)&BsLo[nn][lk * 8];
        }
#pragma unroll
        for (int i = 0; i < 4; i++)
#pragma unroll
            for (int j = 0; j < 4; j++) {
                acc[i][j] = __builtin_amdgcn_mfma_f32_16x16x32_bf16(ah[i], bh[j], acc[i][j], 0, 0, 0);
                acc[i][j] = __builtin_amdgcn_mfma_f32_16x16x32_bf16(ah[i], bl[j], acc[i][j], 0, 0, 0);
                acc[i][j] = __builtin_amdgcn_mfma_f32_16x16x32_bf16(al[i], bh[j], acc[i][j], 0, 0, 0);
            }
        __syncthreads();
    }

#pragma unroll
    for (int i = 0; i < 4; i++) {
#pragma unroll
        for (int j = 0; j < 4; j++) {
#pragma unroll
            for (int q = 0; q < 4; q++) {
                int r = row0 + wr * 64 + i * 16 + lk * 4 + q;
                int c = col0 + wc * 64 + j * 16 + l16;
                if (r < M) {
                    float v = acc[i][j][q];
                    if constexpr (EPI_RELU) v = fmaxf(v + bias[c], 0.f) * rowscale[r];
                    C[(size_t)r * NOUT + c] = v;
                }
            }
        }
    }
}

extern "C" void kernel_launch(void* const* d_in, const int* in_sizes, int n_in,
                              void* d_out, int out_size, void* d_ws, size_t ws_size,
                              hipStream_t stream) {
    const float* x  = (const float*)d_in[0];
    const int*   src = (const int*)d_in[1];
    const int*   dst = (const int*)d_in[2];
    const float* W1 = (const float*)d_in[3];
    const float* b1 = (const float*)d_in[4];
    const float* W2 = (const float*)d_in[5];
    const float* b2 = (const float*)d_in[6];
    float* out = (float*)d_out;

    const int N = N_NODES, E = N_EDGES;

    size_t off = 0;
    auto carve = [&](size_t bytes) -> void* {
        void* p = (char*)d_ws + off;
        off += (bytes + 255) & ~(size_t)255;
        return p;
    };
    int* curA     = (int*)carve(NB * 4);
    int* curB     = (int*)carve(NB * 4);
    int* bstart   = (int*)carve((NB + 1) * 4);
    int* rowstart = (int*)carve((size_t)(N + 1) * 4);
    float* ndst   = (float*)carve((size_t)N * 4);
    float* nsrc   = (float*)carve((size_t)N * 4);
    int* csr      = (int*)carve((size_t)E * 4);
    ushort* Wt1Hi = (ushort*)carve(DIN * DHID * 2);
    ushort* Wt1Lo = (ushort*)carve(DIN * DHID * 2);
    ushort* Wt2Hi = (ushort*)carve(DHID * DOUT * 2);
    ushort* Wt2Lo = (ushort*)carve(DHID * DOUT * 2);
    float* agg1   = (float*)carve((size_t)N * DIN * 4);   // reused as t after GEMM2
    float* h1s    = (float*)carve((size_t)N * DHID * 4);

    // bucket scratch aliases h1s (dead until GEMM1, which runs after both P2 passes)
    uint2* ppair = (uint2*)h1s;                             // 256*8192*8 = 16.8 MB
    int*   psv   = (int*)((char*)h1s + (size_t)NB * CAP * 8);  // +8.4 MB  (<= 102 MB)

    // zero bucket cursors (curA, curB contiguous)
    hipMemsetAsync(curA, 0, 2 * NB * 4, stream);

    part_kernel<<<NBLK1, 256, 0, stream>>>(src, dst, curA, curB, ppair, psv, E);
    bscan_kernel<<<1, 256, 0, stream>>>(curA, bstart, rowstart, N, E);
    csr_kernel<<<NB, 512, 0, stream>>>(curA, bstart, ppair, csr, rowstart, ndst, N);
    nsrc_kernel<<<NB, 512, 0, stream>>>(curB, psv, nsrc, N);

    wconv_kernel<<<(DIN * DHID + 255) / 256, 256, 0, stream>>>(W1, Wt1Hi, Wt1Lo, DIN, DHID);
    wconv_kernel<<<(DHID * DOUT + 255) / 256, 256, 0, stream>>>(W2, Wt2Hi, Wt2Lo, DHID, DOUT);

    // layer 1 aggregation: agg1 = norm_dst * segsum((x*norm_src)[src])
    agg4_kernel<true, false><<<(N + 7) / 8, 256, 0, stream>>>(x, csr, rowstart, nsrc, ndst, nullptr, agg1, N);

    // GEMM1: h1s = relu(agg1 @ W1 + b1) * norm_src
    dim3 g1((N + 127) / 128, DHID / 128);
    mgemm_kernel<DIN, DHID, true><<<g1, 256, 0, stream>>>(agg1, Wt1Hi, Wt1Lo, b1, nsrc, h1s, N);

    // GEMM2: t = h1s @ W2   (t overwrites agg1 buffer)
    float* tbuf = agg1;
    dim3 g2((N + 127) / 128, DOUT / 128);
    mgemm_kernel<DHID, DOUT, false><<<g2, 256, 0, stream>>>(h1s, Wt2Hi, Wt2Lo, nullptr, nullptr, tbuf, N);

    // layer 2 aggregation: out = norm_dst * segsum(t[src]) + b2
    agg4_kernel<false, true><<<(N + 7) / 8, 256, 0, stream>>>(tbuf, csr, rowstart, nullptr, ndst, b2, out, N);
}

// Round 4
// 319.136 us; speedup vs baseline: 2.3504x; 1.3365x over previous
//
#include <hip/hip_runtime.h>

constexpr int N_NODES = 100000;
constexpr int N_EDGES = 1600000;
constexpr int DIN = 128, DHID = 256, DOUT = 128;

constexpr int NB = 256;    // buckets
constexpr int BR = 391;    // node range per bucket (256*391 = 100096 >= N)
constexpr int CAP = 8192;  // per-bucket capacity (mean 6250)
constexpr int NBLK1 = 512;
constexpr int CHUNK = (N_EDGES + NBLK1 - 1) / NBLK1;  // 3125

typedef __bf16 bf16x8 __attribute__((ext_vector_type(8)));
typedef float f32x4 __attribute__((ext_vector_type(4)));

static __device__ __forceinline__ ushort f2bf(float f) {
    uint u = __float_as_uint(f);
    uint r = (u + 0x7FFFu + ((u >> 16) & 1u)) >> 16;
    return (ushort)r;
}
static __device__ __forceinline__ float bf2f(ushort h) {
    return __uint_as_float(((uint)h) << 16);
}

// ---------------- pass 1: partition edges into 256 buckets by dst/BR and src/BR ----------------
__global__ __launch_bounds__(256) void part_kernel(const int* __restrict__ src,
                                                   const int* __restrict__ dst,
                                                   int* __restrict__ curA, int* __restrict__ curB,
                                                   uint2* __restrict__ ppair,
                                                   int* __restrict__ psv, int e) {
    __shared__ uint2 estage[CHUNK];
    __shared__ int hA[NB], hB[NB], rA[NB], rB[NB], cA[NB], cB[NB];
    const int t = threadIdx.x;
    const int b0 = blockIdx.x * CHUNK;
    const int cnt = min(e - b0, CHUNK);
    hA[t] = 0; hB[t] = 0; cA[t] = 0; cB[t] = 0;
    __syncthreads();
    for (int i = t; i < cnt; i += 256) {
        int s = src[b0 + i], d = dst[b0 + i];
        estage[i] = make_uint2((uint)d, (uint)s);
        atomicAdd(&hA[d / BR], 1);
        atomicAdd(&hB[s / BR], 1);
    }
    __syncthreads();
    rA[t] = atomicAdd(&curA[t], hA[t]);  // global reservation (256/block)
    rB[t] = atomicAdd(&curB[t], hB[t]);
    __syncthreads();
    for (int i = t; i < cnt; i += 256) {
        uint2 ed = estage[i];
        int bd = (int)ed.x / BR;
        int bs = (int)ed.y / BR;
        int p = rA[bd] + atomicAdd(&cA[bd], 1);
        if (p < CAP) ppair[(size_t)bd * CAP + p] = ed;
        int q = rB[bs] + atomicAdd(&cB[bs], 1);
        if (q < CAP) psv[(size_t)bs * CAP + q] = (int)ed.y;
    }
}

// ---------------- exclusive scan over 256 bucket counts ----------------
__global__ __launch_bounds__(256) void bscan_kernel(const int* __restrict__ curA,
                                                    int* __restrict__ bstart,
                                                    int* __restrict__ rowstart, int n, int e) {
    __shared__ int s[256];
    int t = threadIdx.x;
    int v = curA[t];
    s[t] = v;
    __syncthreads();
    for (int off = 1; off < 256; off <<= 1) {
        int add = (t >= off) ? s[t - off] : 0;
        __syncthreads();
        s[t] += add;
        __syncthreads();
    }
    bstart[t] = s[t] - v;  // exclusive
    if (t == 255) {
        bstart[256] = s[255];
        rowstart[n] = e;
    }
}

// ---------------- pass 2a: per-bucket CSR build + rowstart + ndst (LDS atomics only) ---------
__global__ __launch_bounds__(512) void csr_kernel(const int* __restrict__ curA,
                                                  const int* __restrict__ bstart,
                                                  const uint2* __restrict__ ppair,
                                                  int* __restrict__ csr,
                                                  int* __restrict__ rowstart,
                                                  float* __restrict__ ndst, int n) {
    __shared__ ushort dloc[CAP];  // 16KB
    __shared__ uint sloc[CAP];    // 32KB
    __shared__ int hist[512], sc[512], exc[512], cur[512];
    const int t = threadIdx.x;
    const int b = blockIdx.x;
    const int first = b * BR;
    const int nr = min(BR, n - first);
    const int cnt = min(curA[b], CAP);
    const size_t base = (size_t)b * CAP;
    const int bst = bstart[b];
    hist[t] = 0;
    cur[t] = 0;
    __syncthreads();
    for (int i = t; i < cnt; i += 512) {
        uint2 ed = ppair[base + i];
        int dl = (int)ed.x - first;
        dloc[i] = (ushort)dl;
        sloc[i] = ed.y;
        atomicAdd(&hist[dl], 1);
    }
    __syncthreads();
    int h = hist[t];
    sc[t] = h;
    __syncthreads();
    for (int off = 1; off < 512; off <<= 1) {
        int add = (t >= off) ? sc[t - off] : 0;
        __syncthreads();
        sc[t] += add;
        __syncthreads();
    }
    exc[t] = sc[t] - h;
    if (t < nr) {
        rowstart[first + t] = bst + exc[t];
        ndst[first + t] = rsqrtf(fmaxf((float)h, 1.0f));
    }
    __syncthreads();
    for (int i = t; i < cnt; i += 512) {
        int dl = dloc[i];
        int p = exc[dl] + atomicAdd(&cur[dl], 1);
        csr[bst + p] = (int)sloc[i];
    }
}

// ---------------- pass 2b: per-bucket out-degree -> nsrc (LDS atomics only) ----------------
__global__ __launch_bounds__(512) void nsrc_kernel(const int* __restrict__ curB,
                                                   const int* __restrict__ psv,
                                                   float* __restrict__ nsrc, int n) {
    __shared__ int hist[512];
    const int t = threadIdx.x;
    const int b = blockIdx.x;
    const int first = b * BR;
    const int nr = min(BR, n - first);
    const int cnt = min(curB[b], CAP);
    const size_t base = (size_t)b * CAP;
    hist[t] = 0;
    __syncthreads();
    for (int i = t; i < cnt; i += 512) atomicAdd(&hist[psv[base + i] - first], 1);
    __syncthreads();
    if (t < nr) nsrc[first + t] = rsqrtf(fmaxf((float)hist[t], 1.0f));
}

// ---------------- xb = bf16(x * nsrc[row]) ----------------
__global__ __launch_bounds__(256) void xbconv_kernel(const float* __restrict__ x,
                                                     const float* __restrict__ nsrc,
                                                     ushort* __restrict__ xb, int n) {
    int i = blockIdx.x * 256 + threadIdx.x;  // one per 4 floats
    if (i >= n * 32) return;
    int row = i >> 5;
    float s = nsrc[row];
    float4 v = *(const float4*)&x[(size_t)i * 4];
    ushort4 o = {f2bf(v.x * s), f2bf(v.y * s), f2bf(v.z * s), f2bf(v.w * s)};
    *(ushort4*)&xb[(size_t)i * 4] = o;
}

// ---------------- W pre-convert: fp32 [K][N] -> transposed bf16 hi/lo [N][K] ----------------
__global__ void wconv_kernel(const float* __restrict__ W, ushort* __restrict__ hi,
                             ushort* __restrict__ lo, int K, int N) {
    int i = blockIdx.x * blockDim.x + threadIdx.x;
    if (i < K * N) {
        int k = i / N;
        int n = i - k * N;
        float w = W[i];
        ushort h = f2bf(w);
        ushort l = f2bf(w - bf2f(h));
        hi[(size_t)n * K + k] = h;
        lo[(size_t)n * K + k] = l;
    }
}

// ---------------- bf16 gather-aggregate: 8 dst rows / block, ushort4 per lane-of-32 ----------
template <bool ADDBIAS>
__global__ __launch_bounds__(256) void aggb_kernel(const ushort* __restrict__ Xb,
                                                   const int* __restrict__ csr,
                                                   const int* __restrict__ rowstart,
                                                   const float* __restrict__ ndst,
                                                   const float* __restrict__ bias,
                                                   float* __restrict__ out, int n) {
    int rl = threadIdx.x >> 5;    // 0..7
    int lane = threadIdx.x & 31;  // feature group: [lane*4, lane*4+4)
    int d = blockIdx.x * 8 + rl;
    if (d >= n) return;
    int beg = rowstart[d], end = rowstart[d + 1];
    float ax = 0.f, ay = 0.f, az = 0.f, aw = 0.f;
    int fo = lane * 4;
    int k = beg;
    for (; k + 4 <= end; k += 4) {
        int s0 = csr[k], s1 = csr[k + 1], s2 = csr[k + 2], s3 = csr[k + 3];
        ushort4 x0 = *(const ushort4*)&Xb[(size_t)s0 * 128 + fo];
        ushort4 x1 = *(const ushort4*)&Xb[(size_t)s1 * 128 + fo];
        ushort4 x2 = *(const ushort4*)&Xb[(size_t)s2 * 128 + fo];
        ushort4 x3 = *(const ushort4*)&Xb[(size_t)s3 * 128 + fo];
        ax += bf2f(x0.x) + bf2f(x1.x) + bf2f(x2.x) + bf2f(x3.x);
        ay += bf2f(x0.y) + bf2f(x1.y) + bf2f(x2.y) + bf2f(x3.y);
        az += bf2f(x0.z) + bf2f(x1.z) + bf2f(x2.z) + bf2f(x3.z);
        aw += bf2f(x0.w) + bf2f(x1.w) + bf2f(x2.w) + bf2f(x3.w);
    }
    for (; k < end; ++k) {
        int s = csr[k];
        ushort4 x = *(const ushort4*)&Xb[(size_t)s * 128 + fo];
        ax += bf2f(x.x);
        ay += bf2f(x.y);
        az += bf2f(x.z);
        aw += bf2f(x.w);
    }
    float nd = ndst[d];
    float4 v;
    v.x = ax * nd;
    v.y = ay * nd;
    v.z = az * nd;
    v.w = aw * nd;
    if constexpr (ADDBIAS) {
        const float4 b = *(const float4*)&bias[fo];
        v.x += b.x;
        v.y += b.y;
        v.z += b.z;
        v.w += b.w;
    }
    *(float4*)&out[(size_t)d * 128 + fo] = v;
}

// ---------------- GEMM1: A fp32 (split 3-pass), C = bf16(relu(A@B + bias) * rowscale) --------
template <int K, int NOUT>
__global__ __launch_bounds__(256) void mgemm1_kernel(const float* __restrict__ A,
                                                     const ushort* __restrict__ BtHi,
                                                     const ushort* __restrict__ BtLo,
                                                     const float* __restrict__ bias,
                                                     const float* __restrict__ rowscale,
                                                     ushort* __restrict__ C, int M) {
    constexpr int BM = 128, BN = 128, KB = 32, LDT = 40;
    __shared__ ushort AsHi[BM][LDT], AsLo[BM][LDT], BsHi[BN][LDT], BsLo[BN][LDT];
    const int row0 = blockIdx.x * BM, col0 = blockIdx.y * BN;
    const int t = threadIdx.x;
    const int wid = t >> 6, lane = t & 63;
    const int wr = wid >> 1, wc = wid & 1;
    const int l16 = lane & 15, lk = lane >> 4;

    f32x4 acc[4][4];
#pragma unroll
    for (int i = 0; i < 4; i++)
#pragma unroll
        for (int j = 0; j < 4; j++) acc[i][j] = (f32x4){0.f, 0.f, 0.f, 0.f};

    for (int kb = 0; kb < K; kb += KB) {
#pragma unroll
        for (int i = 0; i < 4; i++) {
            int idx = i * 256 + t;
            int r = idx >> 3, c4 = idx & 7;
            int gr = row0 + r;
            float4 v = make_float4(0.f, 0.f, 0.f, 0.f);
            if (gr < M) v = *(const float4*)&A[(size_t)gr * K + kb + c4 * 4];
            ushort h0 = f2bf(v.x), h1 = f2bf(v.y), h2 = f2bf(v.z), h3 = f2bf(v.w);
            ushort l0 = f2bf(v.x - bf2f(h0)), l1 = f2bf(v.y - bf2f(h1));
            ushort l2 = f2bf(v.z - bf2f(h2)), l3 = f2bf(v.w - bf2f(h3));
            ushort4 hv = {h0, h1, h2, h3};
            ushort4 lv = {l0, l1, l2, l3};
            *(ushort4*)&AsHi[r][c4 * 4] = hv;
            *(ushort4*)&AsLo[r][c4 * 4] = lv;
        }
#pragma unroll
        for (int i = 0; i < 2; i++) {
            int idx = i * 256 + t;
            int r = idx >> 2, s = idx & 3;
            *(uint4*)&BsHi[r][s * 8] = *(const uint4*)&BtHi[(size_t)(col0 + r) * K + kb + s * 8];
            *(uint4*)&BsLo[r][s * 8] = *(const uint4*)&BtLo[(size_t)(col0 + r) * K + kb + s * 8];
        }
        __syncthreads();

        bf16x8 ah[4], al[4], bh[4], bl[4];
#pragma unroll
        for (int i = 0; i < 4; i++) {
            int m = wr * 64 + i * 16 + l16;
            ah[i] = *(const bf16x8*)&AsHi[m][lk * 8];
            al[i] = *(const bf16x8*)&AsLo[m][lk * 8];
            int nn = wc * 64 + i * 16 + l16;
            bh[i] = *(const bf16x8*)&BsHi[nn][lk * 8];
            bl[i] = *(const bf16x8*)&BsLo[nn][lk * 8];
        }
#pragma unroll
        for (int i = 0; i < 4; i++)
#pragma unroll
            for (int j = 0; j < 4; j++) {
                acc[i][j] = __builtin_amdgcn_mfma_f32_16x16x32_bf16(ah[i], bh[j], acc[i][j], 0, 0, 0);
                acc[i][j] = __builtin_amdgcn_mfma_f32_16x16x32_bf16(ah[i], bl[j], acc[i][j], 0, 0, 0);
                acc[i][j] = __builtin_amdgcn_mfma_f32_16x16x32_bf16(al[i], bh[j], acc[i][j], 0, 0, 0);
            }
        __syncthreads();
    }

#pragma unroll
    for (int i = 0; i < 4; i++) {
#pragma unroll
        for (int j = 0; j < 4; j++) {
#pragma unroll
            for (int q = 0; q < 4; q++) {
                int r = row0 + wr * 64 + i * 16 + lk * 4 + q;
                int c = col0 + wc * 64 + j * 16 + l16;
                if (r < M) {
                    float v = fmaxf(acc[i][j][q] + bias[c], 0.f) * rowscale[r];
                    C[(size_t)r * NOUT + c] = f2bf(v);
                }
            }
        }
    }
}

// ---------------- GEMM2: A bf16 (2-pass), C = bf16(A@B) ----------------
template <int K, int NOUT>
__global__ __launch_bounds__(256) void mgemm2_kernel(const ushort* __restrict__ A,
                                                     const ushort* __restrict__ BtHi,
                                                     const ushort* __restrict__ BtLo,
                                                     ushort* __restrict__ C, int M) {
    constexpr int BM = 128, BN = 128, KB = 32, LDT = 40;
    __shared__ ushort As[BM][LDT], BsHi[BN][LDT], BsLo[BN][LDT];
    const int row0 = blockIdx.x * BM, col0 = blockIdx.y * BN;
    const int t = threadIdx.x;
    const int wid = t >> 6, lane = t & 63;
    const int wr = wid >> 1, wc = wid & 1;
    const int l16 = lane & 15, lk = lane >> 4;

    f32x4 acc[4][4];
#pragma unroll
    for (int i = 0; i < 4; i++)
#pragma unroll
        for (int j = 0; j < 4; j++) acc[i][j] = (f32x4){0.f, 0.f, 0.f, 0.f};

    for (int kb = 0; kb < K; kb += KB) {
#pragma unroll
        for (int i = 0; i < 2; i++) {
            int idx = i * 256 + t;  // 0..511 uint4-pieces (A tile: 128 rows x 4 pieces)
            int r = idx >> 2, s = idx & 3;
            int gr = row0 + r;
            uint4 v = make_uint4(0u, 0u, 0u, 0u);
            if (gr < M) v = *(const uint4*)&A[(size_t)gr * K + kb + s * 8];
            *(uint4*)&As[r][s * 8] = v;
        }
#pragma unroll
        for (int i = 0; i < 2; i++) {
            int idx = i * 256 + t;
            int r = idx >> 2, s = idx & 3;
            *(uint4*)&BsHi[r][s * 8] = *(const uint4*)&BtHi[(size_t)(col0 + r) * K + kb + s * 8];
            *(uint4*)&BsLo[r][s * 8] = *(const uint4*)&BtLo[(size_t)(col0 + r) * K + kb + s * 8];
        }
        __syncthreads();

        bf16x8 ah[4], bh[4], bl[4];
#pragma unroll
        for (int i = 0; i < 4; i++) {
            int m = wr * 64 + i * 16 + l16;
            ah[i] = *(const bf16x8*)&As[m][lk * 8];
            int nn = wc * 64 + i * 16 + l16;
            bh[i] = *(const bf16x8*)&BsHi[nn][lk * 8];
            bl[i] = *(const bf16x8*)&BsLo[nn][lk * 8];
        }
#pragma unroll
        for (int i = 0; i < 4; i++)
#pragma unroll
            for (int j = 0; j < 4; j++) {
                acc[i][j] = __builtin_amdgcn_mfma_f32_16x16x32_bf16(ah[i], bh[j], acc[i][j], 0, 0, 0);
                acc[i][j] = __builtin_amdgcn_mfma_f32_16x16x32_bf16(ah[i], bl[j], acc[i][j], 0, 0, 0);
            }
        __syncthreads();
    }

#pragma unroll
    for (int i = 0; i < 4; i++) {
#pragma unroll
        for (int j = 0; j < 4; j++) {
#pragma unroll
            for (int q = 0; q < 4; q++) {
                int r = row0 + wr * 64 + i * 16 + lk * 4 + q;
                int c = col0 + wc * 64 + j * 16 + l16;
                if (r < M) C[(size_t)r * NOUT + c] = f2bf(acc[i][j][q]);
            }
        }
    }
}

extern "C" void kernel_launch(void* const* d_in, const int* in_sizes, int n_in,
                              void* d_out, int out_size, void* d_ws, size_t ws_size,
                              hipStream_t stream) {
    const float* x  = (const float*)d_in[0];
    const int*   src = (const int*)d_in[1];
    const int*   dst = (const int*)d_in[2];
    const float* W1 = (const float*)d_in[3];
    const float* b1 = (const float*)d_in[4];
    const float* W2 = (const float*)d_in[5];
    const float* b2 = (const float*)d_in[6];
    float* out = (float*)d_out;

    const int N = N_NODES, E = N_EDGES;

    size_t off = 0;
    auto carve = [&](size_t bytes) -> void* {
        void* p = (char*)d_ws + off;
        off += (bytes + 255) & ~(size_t)255;
        return p;
    };
    int* curA     = (int*)carve(NB * 4);
    int* curB     = (int*)carve(NB * 4);
    int* bstart   = (int*)carve((NB + 1) * 4);
    int* rowstart = (int*)carve((size_t)(N + 1) * 4);
    float* ndst   = (float*)carve((size_t)N * 4);
    float* nsrc   = (float*)carve((size_t)N * 4);
    int* csr      = (int*)carve((size_t)E * 4);
    ushort* Wt1Hi = (ushort*)carve(DIN * DHID * 2);
    ushort* Wt1Lo = (ushort*)carve(DIN * DHID * 2);
    ushort* Wt2Hi = (ushort*)carve(DHID * DOUT * 2);
    ushort* Wt2Lo = (ushort*)carve(DHID * DOUT * 2);
    ushort* xb    = (ushort*)carve((size_t)N * DIN * 2);   // bf16(x*nsrc)
    float*  agg1  = (float*)carve((size_t)N * DIN * 4);    // fp32 aggregate (GEMM1 A)
    ushort* h1b   = (ushort*)carve((size_t)N * DHID * 2);  // bf16(relu(h1)*nsrc)
    ushort* tb    = (ushort*)carve((size_t)N * DOUT * 2);  // bf16(h1b @ W2)

    // bucket scratch aliases h1b (dead until GEMM1, which runs after both P2 passes)
    uint2* ppair = (uint2*)h1b;                                // 256*8192*8 = 16.8 MB
    int*   psv   = (int*)((char*)h1b + (size_t)NB * CAP * 8);  // +8.4 MB (h1b = 51.2 MB)

    hipMemsetAsync(curA, 0, 2 * NB * 4, stream);

    part_kernel<<<NBLK1, 256, 0, stream>>>(src, dst, curA, curB, ppair, psv, E);
    bscan_kernel<<<1, 256, 0, stream>>>(curA, bstart, rowstart, N, E);
    csr_kernel<<<NB, 512, 0, stream>>>(curA, bstart, ppair, csr, rowstart, ndst, N);
    nsrc_kernel<<<NB, 512, 0, stream>>>(curB, psv, nsrc, N);

    xbconv_kernel<<<(N * 32 + 255) / 256, 256, 0, stream>>>(x, nsrc, xb, N);
    wconv_kernel<<<(DIN * DHID + 255) / 256, 256, 0, stream>>>(W1, Wt1Hi, Wt1Lo, DIN, DHID);
    wconv_kernel<<<(DHID * DOUT + 255) / 256, 256, 0, stream>>>(W2, Wt2Hi, Wt2Lo, DHID, DOUT);

    // layer 1 aggregation: agg1 = ndst * segsum(xb[src])   (nsrc pre-folded into xb)
    aggb_kernel<false><<<(N + 7) / 8, 256, 0, stream>>>(xb, csr, rowstart, ndst, nullptr, agg1, N);

    // GEMM1: h1b = bf16(relu(agg1 @ W1 + b1) * nsrc)
    dim3 g1((N + 127) / 128, DHID / 128);
    mgemm1_kernel<DIN, DHID><<<g1, 256, 0, stream>>>(agg1, Wt1Hi, Wt1Lo, b1, nsrc, h1b, N);

    // GEMM2: tb = bf16(h1b @ W2)
    dim3 g2((N + 127) / 128, DOUT / 128);
    mgemm2_kernel<DHID, DOUT><<<g2, 256, 0, stream>>>(h1b, Wt2Hi, Wt2Lo, tb, N);

    // layer 2 aggregation: out = ndst * segsum(tb[src]) + b2
    aggb_kernel<true><<<(N + 7) / 8, 256, 0, stream>>>(tb, csr, rowstart, ndst, b2, out, N);
}

// Round 5
// 273.628 us; speedup vs baseline: 2.7414x; 1.1663x over previous
//
#include <hip/hip_runtime.h>

constexpr int N_NODES = 100000;
constexpr int N_EDGES = 1600000;
constexpr int DIN = 128, DHID = 256, DOUT = 128;

constexpr int NB = 256;    // buckets
constexpr int BR = 391;    // node range per bucket (256*391 = 100096 >= N)
constexpr int CAP = 8192;  // per-bucket capacity (mean 6250)
constexpr int NBLK1 = 512;
constexpr int CHUNK = (N_EDGES + NBLK1 - 1) / NBLK1;  // 3125

typedef __bf16 bf16x8 __attribute__((ext_vector_type(8)));
typedef float f32x4 __attribute__((ext_vector_type(4)));

static __device__ __forceinline__ ushort f2bf(float f) {
    uint u = __float_as_uint(f);
    uint r = (u + 0x7FFFu + ((u >> 16) & 1u)) >> 16;
    return (ushort)r;
}
static __device__ __forceinline__ float bf2f(ushort h) {
    return __uint_as_float(((uint)h) << 16);
}

// ---------------- pass 1: partition edges into 256 buckets by dst/BR and src/BR ----------------
__global__ __launch_bounds__(256) void part_kernel(const int* __restrict__ src,
                                                   const int* __restrict__ dst,
                                                   int* __restrict__ curA, int* __restrict__ curB,
                                                   uint2* __restrict__ ppair,
                                                   int* __restrict__ psv, int e) {
    __shared__ uint2 estage[CHUNK];
    __shared__ int hA[NB], hB[NB], rA[NB], rB[NB], cA[NB], cB[NB];
    const int t = threadIdx.x;
    const int b0 = blockIdx.x * CHUNK;
    const int cnt = min(e - b0, CHUNK);
    hA[t] = 0; hB[t] = 0; cA[t] = 0; cB[t] = 0;
    __syncthreads();
    for (int i = t; i < cnt; i += 256) {
        int s = src[b0 + i], d = dst[b0 + i];
        estage[i] = make_uint2((uint)d, (uint)s);
        atomicAdd(&hA[d / BR], 1);
        atomicAdd(&hB[s / BR], 1);
    }
    __syncthreads();
    rA[t] = atomicAdd(&curA[t], hA[t]);  // global reservation (256/block)
    rB[t] = atomicAdd(&curB[t], hB[t]);
    __syncthreads();
    for (int i = t; i < cnt; i += 256) {
        uint2 ed = estage[i];
        int bd = (int)ed.x / BR;
        int bs = (int)ed.y / BR;
        int p = rA[bd] + atomicAdd(&cA[bd], 1);
        if (p < CAP) ppair[(size_t)bd * CAP + p] = ed;
        int q = rB[bs] + atomicAdd(&cB[bs], 1);
        if (q < CAP) psv[(size_t)bs * CAP + q] = (int)ed.y;
    }
}

// ---------------- exclusive scan over 256 bucket counts ----------------
__global__ __launch_bounds__(256) void bscan_kernel(const int* __restrict__ curA,
                                                    int* __restrict__ bstart,
                                                    int* __restrict__ rowstart, int n, int e) {
    __shared__ int s[256];
    int t = threadIdx.x;
    int v = curA[t];
    s[t] = v;
    __syncthreads();
    for (int off = 1; off < 256; off <<= 1) {
        int add = (t >= off) ? s[t - off] : 0;
        __syncthreads();
        s[t] += add;
        __syncthreads();
    }
    bstart[t] = s[t] - v;  // exclusive
    if (t == 255) {
        bstart[256] = s[255];
        rowstart[n] = e;
    }
}

// ---------------- pass 2a: per-bucket CSR build + rowstart + ndst (LDS atomics only) ---------
__global__ __launch_bounds__(512) void csr_kernel(const int* __restrict__ curA,
                                                  const int* __restrict__ bstart,
                                                  const uint2* __restrict__ ppair,
                                                  int* __restrict__ csr,
                                                  int* __restrict__ rowstart,
                                                  float* __restrict__ ndst, int n) {
    __shared__ ushort dloc[CAP];  // 16KB
    __shared__ uint sloc[CAP];    // 32KB
    __shared__ int hist[512], sc[512], exc[512], cur[512];
    const int t = threadIdx.x;
    const int b = blockIdx.x;
    const int first = b * BR;
    const int nr = min(BR, n - first);
    const int cnt = min(curA[b], CAP);
    const size_t base = (size_t)b * CAP;
    const int bst = bstart[b];
    hist[t] = 0;
    cur[t] = 0;
    __syncthreads();
    for (int i = t; i < cnt; i += 512) {
        uint2 ed = ppair[base + i];
        int dl = (int)ed.x - first;
        dloc[i] = (ushort)dl;
        sloc[i] = ed.y;
        atomicAdd(&hist[dl], 1);
    }
    __syncthreads();
    int h = hist[t];
    sc[t] = h;
    __syncthreads();
    for (int off = 1; off < 512; off <<= 1) {
        int add = (t >= off) ? sc[t - off] : 0;
        __syncthreads();
        sc[t] += add;
        __syncthreads();
    }
    exc[t] = sc[t] - h;
    if (t < nr) {
        rowstart[first + t] = bst + exc[t];
        ndst[first + t] = rsqrtf(fmaxf((float)h, 1.0f));
    }
    __syncthreads();
    for (int i = t; i < cnt; i += 512) {
        int dl = dloc[i];
        int p = exc[dl] + atomicAdd(&cur[dl], 1);
        csr[bst + p] = (int)sloc[i];
    }
}

// ---------------- pass 2b: per-bucket out-degree -> nsrc (LDS atomics only) ----------------
__global__ __launch_bounds__(512) void nsrc_kernel(const int* __restrict__ curB,
                                                   const int* __restrict__ psv,
                                                   float* __restrict__ nsrc, int n) {
    __shared__ int hist[512];
    const int t = threadIdx.x;
    const int b = blockIdx.x;
    const int first = b * BR;
    const int nr = min(BR, n - first);
    const int cnt = min(curB[b], CAP);
    const size_t base = (size_t)b * CAP;
    hist[t] = 0;
    __syncthreads();
    for (int i = t; i < cnt; i += 512) atomicAdd(&hist[psv[base + i] - first], 1);
    __syncthreads();
    if (t < nr) nsrc[first + t] = rsqrtf(fmaxf((float)hist[t], 1.0f));
}

// ---------------- xb = bf16(x * nsrc[row]) ----------------
__global__ __launch_bounds__(256) void xbconv_kernel(const float* __restrict__ x,
                                                     const float* __restrict__ nsrc,
                                                     ushort* __restrict__ xb, int n) {
    int i = blockIdx.x * 256 + threadIdx.x;  // one per 4 floats
    if (i >= n * 32) return;
    int row = i >> 5;
    float s = nsrc[row];
    float4 v = *(const float4*)&x[(size_t)i * 4];
    ushort4 o = {f2bf(v.x * s), f2bf(v.y * s), f2bf(v.z * s), f2bf(v.w * s)};
    *(ushort4*)&xb[(size_t)i * 4] = o;
}

// ---------------- W pre-convert: fp32 [K][N] -> transposed bf16 [N][K] ----------------
__global__ void wconv_kernel(const float* __restrict__ W, ushort* __restrict__ wt, int K, int N) {
    int i = blockIdx.x * blockDim.x + threadIdx.x;
    if (i < K * N) {
        int k = i / N;
        int n = i - k * N;
        wt[(size_t)n * K + k] = f2bf(W[i]);
    }
}

// ---------------- bf16 gather-aggregate: 8 dst rows / block, ushort4 per lane-of-32 ----------
// OUTBF16: write bf16 (layer 1, feeds GEMM1).  else fp32 (+bias) (layer 2 output).
template <bool OUTBF16, bool ADDBIAS>
__global__ __launch_bounds__(256) void aggb_kernel(const ushort* __restrict__ Xb,
                                                   const int* __restrict__ csr,
                                                   const int* __restrict__ rowstart,
                                                   const float* __restrict__ ndst,
                                                   const float* __restrict__ bias,
                                                   float* __restrict__ outf,
                                                   ushort* __restrict__ outb, int n) {
    int rl = threadIdx.x >> 5;    // 0..7
    int lane = threadIdx.x & 31;  // feature group: [lane*4, lane*4+4)
    int d = blockIdx.x * 8 + rl;
    if (d >= n) return;
    int beg = rowstart[d], end = rowstart[d + 1];
    float ax = 0.f, ay = 0.f, az = 0.f, aw = 0.f;
    int fo = lane * 4;
    int k = beg;
    for (; k + 4 <= end; k += 4) {
        int s0 = csr[k], s1 = csr[k + 1], s2 = csr[k + 2], s3 = csr[k + 3];
        ushort4 x0 = *(const ushort4*)&Xb[(size_t)s0 * 128 + fo];
        ushort4 x1 = *(const ushort4*)&Xb[(size_t)s1 * 128 + fo];
        ushort4 x2 = *(const ushort4*)&Xb[(size_t)s2 * 128 + fo];
        ushort4 x3 = *(const ushort4*)&Xb[(size_t)s3 * 128 + fo];
        ax += bf2f(x0.x) + bf2f(x1.x) + bf2f(x2.x) + bf2f(x3.x);
        ay += bf2f(x0.y) + bf2f(x1.y) + bf2f(x2.y) + bf2f(x3.y);
        az += bf2f(x0.z) + bf2f(x1.z) + bf2f(x2.z) + bf2f(x3.z);
        aw += bf2f(x0.w) + bf2f(x1.w) + bf2f(x2.w) + bf2f(x3.w);
    }
    for (; k < end; ++k) {
        int s = csr[k];
        ushort4 x = *(const ushort4*)&Xb[(size_t)s * 128 + fo];
        ax += bf2f(x.x);
        ay += bf2f(x.y);
        az += bf2f(x.z);
        aw += bf2f(x.w);
    }
    float nd = ndst[d];
    float4 v;
    v.x = ax * nd;
    v.y = ay * nd;
    v.z = az * nd;
    v.w = aw * nd;
    if constexpr (ADDBIAS) {
        const float4 b = *(const float4*)&bias[fo];
        v.x += b.x;
        v.y += b.y;
        v.z += b.z;
        v.w += b.w;
    }
    if constexpr (OUTBF16) {
        ushort4 o = {f2bf(v.x), f2bf(v.y), f2bf(v.z), f2bf(v.w)};
        *(ushort4*)&outb[(size_t)d * 128 + fo] = o;
    } else {
        *(float4*)&outf[(size_t)d * 128 + fo] = v;
    }
}

// ---------------- pure-bf16 MFMA GEMM: C = epi(A @ B) as bf16 ----------------
// BM=BN=128, KB=32, 256 threads = 4 waves (2x2), wave = 64x64 = 4x4 frags of 16x16x32.
// LDS 16KB, group-of-8 XOR swizzle (g ^= (row>>2)&3) -> conflict-free b128 reads.
template <int K, int NOUT, bool EPI_RELU>
__global__ __launch_bounds__(256) void bgemm_kernel(const ushort* __restrict__ A,
                                                    const ushort* __restrict__ Bt,
                                                    const float* __restrict__ bias,
                                                    const float* __restrict__ rowscale,
                                                    ushort* __restrict__ C, int M) {
    constexpr int BM = 128, BN = 128, KB = 32, LDT = 32;
    __shared__ ushort As[BM][LDT], Bs[BN][LDT];
    const int row0 = blockIdx.x * BM, col0 = blockIdx.y * BN;
    const int t = threadIdx.x;
    const int wid = t >> 6, lane = t & 63;
    const int wr = wid >> 1, wc = wid & 1;
    const int l16 = lane & 15, lk = lane >> 4;
    const int sw = (l16 >> 2) & 3;  // read-side swizzle (row>>2)&3 for rows i*16+l16

    f32x4 acc[4][4];
#pragma unroll
    for (int i = 0; i < 4; i++)
#pragma unroll
        for (int j = 0; j < 4; j++) acc[i][j] = (f32x4){0.f, 0.f, 0.f, 0.f};

    for (int kb = 0; kb < K; kb += KB) {
#pragma unroll
        for (int i = 0; i < 2; i++) {
            int idx = i * 256 + t;          // 0..511 uint4-pieces
            int r = idx >> 2, s = idx & 3;  // row, k-octet
            int g = s ^ ((r >> 2) & 3);     // swizzled group
            int gr = row0 + r;
            uint4 v = make_uint4(0u, 0u, 0u, 0u);
            if (gr < M) v = *(const uint4*)&A[(size_t)gr * K + kb + s * 8];
            *(uint4*)&As[r][g * 8] = v;
            *(uint4*)&Bs[r][g * 8] = *(const uint4*)&Bt[(size_t)(col0 + r) * K + kb + s * 8];
        }
        __syncthreads();

        bf16x8 a[4], b[4];
#pragma unroll
        for (int i = 0; i < 4; i++) {
            a[i] = *(const bf16x8*)&As[wr * 64 + i * 16 + l16][(lk ^ sw) * 8];
            b[i] = *(const bf16x8*)&Bs[wc * 64 + i * 16 + l16][(lk ^ sw) * 8];
        }
#pragma unroll
        for (int i = 0; i < 4; i++)
#pragma unroll
            for (int j = 0; j < 4; j++)
                acc[i][j] = __builtin_amdgcn_mfma_f32_16x16x32_bf16(a[i], b[j], acc[i][j], 0, 0, 0);
        __syncthreads();
    }

    // C/D layout: col=lane&15, row=(lane>>4)*4+q  [m89/m91-verified]
#pragma unroll
    for (int i = 0; i < 4; i++) {
#pragma unroll
        for (int j = 0; j < 4; j++) {
#pragma unroll
            for (int q = 0; q < 4; q++) {
                int r = row0 + wr * 64 + i * 16 + lk * 4 + q;
                int c = col0 + wc * 64 + j * 16 + l16;
                if (r < M) {
                    float v = acc[i][j][q];
                    if constexpr (EPI_RELU) v = fmaxf(v + bias[c], 0.f) * rowscale[r];
                    C[(size_t)r * NOUT + c] = f2bf(v);
                }
            }
        }
    }
}

extern "C" void kernel_launch(void* const* d_in, const int* in_sizes, int n_in,
                              void* d_out, int out_size, void* d_ws, size_t ws_size,
                              hipStream_t stream) {
    const float* x  = (const float*)d_in[0];
    const int*   src = (const int*)d_in[1];
    const int*   dst = (const int*)d_in[2];
    const float* W1 = (const float*)d_in[3];
    const float* b1 = (const float*)d_in[4];
    const float* W2 = (const float*)d_in[5];
    const float* b2 = (const float*)d_in[6];
    float* out = (float*)d_out;

    const int N = N_NODES, E = N_EDGES;

    size_t off = 0;
    auto carve = [&](size_t bytes) -> void* {
        void* p = (char*)d_ws + off;
        off += (bytes + 255) & ~(size_t)255;
        return p;
    };
    int* curA     = (int*)carve(NB * 4);
    int* curB     = (int*)carve(NB * 4);
    int* bstart   = (int*)carve((NB + 1) * 4);
    int* rowstart = (int*)carve((size_t)(N + 1) * 4);
    float* ndst   = (float*)carve((size_t)N * 4);
    float* nsrc   = (float*)carve((size_t)N * 4);
    int* csr      = (int*)carve((size_t)E * 4);
    ushort* Wt1   = (ushort*)carve(DIN * DHID * 2);
    ushort* Wt2   = (ushort*)carve(DHID * DOUT * 2);
    ushort* xb    = (ushort*)carve((size_t)N * DIN * 2);   // bf16(x*nsrc)
    ushort* agg1b = (ushort*)carve((size_t)N * DIN * 2);   // bf16 aggregate (GEMM1 A)
    ushort* h1b   = (ushort*)carve((size_t)N * DHID * 2);  // bf16(relu(h1)*nsrc)
    ushort* tb    = (ushort*)carve((size_t)N * DOUT * 2);  // bf16(h1b @ W2)

    // bucket scratch aliases h1b (dead until GEMM1, which runs after both P2 passes)
    uint2* ppair = (uint2*)h1b;                                // 256*8192*8 = 16.8 MB
    int*   psv   = (int*)((char*)h1b + (size_t)NB * CAP * 8);  // +8.4 MB (h1b = 51.2 MB)

    hipMemsetAsync(curA, 0, 2 * NB * 4, stream);

    part_kernel<<<NBLK1, 256, 0, stream>>>(src, dst, curA, curB, ppair, psv, E);
    bscan_kernel<<<1, 256, 0, stream>>>(curA, bstart, rowstart, N, E);
    csr_kernel<<<NB, 512, 0, stream>>>(curA, bstart, ppair, csr, rowstart, ndst, N);
    nsrc_kernel<<<NB, 512, 0, stream>>>(curB, psv, nsrc, N);

    xbconv_kernel<<<(N * 32 + 255) / 256, 256, 0, stream>>>(x, nsrc, xb, N);
    wconv_kernel<<<(DIN * DHID + 255) / 256, 256, 0, stream>>>(W1, Wt1, DIN, DHID);
    wconv_kernel<<<(DHID * DOUT + 255) / 256, 256, 0, stream>>>(W2, Wt2, DHID, DOUT);

    // layer 1 aggregation: agg1b = bf16(ndst * segsum(xb[src]))
    aggb_kernel<true, false><<<(N + 7) / 8, 256, 0, stream>>>(xb, csr, rowstart, ndst, nullptr,
                                                              nullptr, agg1b, N);

    // GEMM1: h1b = bf16(relu(agg1b @ W1 + b1) * nsrc)
    dim3 g1((N + 127) / 128, DHID / 128);
    bgemm_kernel<DIN, DHID, true><<<g1, 256, 0, stream>>>(agg1b, Wt1, b1, nsrc, h1b, N);

    // GEMM2: tb = bf16(h1b @ W2)
    dim3 g2((N + 127) / 128, DOUT / 128);
    bgemm_kernel<DHID, DOUT, false><<<g2, 256, 0, stream>>>(h1b, Wt2, nullptr, nullptr, tb, N);

    // layer 2 aggregation: out = ndst * segsum(tb[src]) + b2
    aggb_kernel<false, true><<<(N + 7) / 8, 256, 0, stream>>>(tb, csr, rowstart, ndst, b2,
                                                              out, nullptr, N);
}

// Round 6
// 272.367 us; speedup vs baseline: 2.7540x; 1.0046x over previous
//
#include <hip/hip_runtime.h>

constexpr int N_NODES = 100000;
constexpr int N_EDGES = 1600000;
constexpr int DIN = 128, DHID = 256, DOUT = 128;

constexpr int NB = 256;    // buckets
constexpr int BR = 391;    // node range per bucket (256*391 = 100096 >= N)
constexpr int CAP = 8192;  // per-bucket capacity (mean 6250)
constexpr int NBLK1 = 512;
constexpr int CHUNK = (N_EDGES + NBLK1 - 1) / NBLK1;  // 3125

typedef __bf16 bf16x8 __attribute__((ext_vector_type(8)));
typedef float f32x4 __attribute__((ext_vector_type(4)));

static __device__ __forceinline__ ushort f2bf(float f) {
    uint u = __float_as_uint(f);
    uint r = (u + 0x7FFFu + ((u >> 16) & 1u)) >> 16;
    return (ushort)r;
}
static __device__ __forceinline__ float bf2f(ushort h) {
    return __uint_as_float(((uint)h) << 16);
}
static __device__ __forceinline__ float bflo(uint w) { return __uint_as_float(w << 16); }
static __device__ __forceinline__ float bfhi(uint w) { return __uint_as_float(w & 0xFFFF0000u); }

// ---------------- pass 1: partition edges into 256 buckets by dst/BR and src/BR ----------------
// (no LDS edge staging: pass 2 re-reads src/dst; the 25KB chunk is L1/L2-resident)
__global__ __launch_bounds__(256) void part_kernel(const int* __restrict__ src,
                                                   const int* __restrict__ dst,
                                                   int* __restrict__ curA, int* __restrict__ curB,
                                                   uint2* __restrict__ ppair,
                                                   int* __restrict__ psv, int e) {
    __shared__ int hA[NB], hB[NB], rA[NB], rB[NB], cA[NB], cB[NB];
    const int t = threadIdx.x;
    const int b0 = blockIdx.x * CHUNK;
    const int cnt = min(e - b0, CHUNK);
    hA[t] = 0; hB[t] = 0; cA[t] = 0; cB[t] = 0;
    __syncthreads();
    for (int i = t; i < cnt; i += 256) {
        int s = src[b0 + i], d = dst[b0 + i];
        atomicAdd(&hA[d / BR], 1);
        atomicAdd(&hB[s / BR], 1);
    }
    __syncthreads();
    rA[t] = atomicAdd(&curA[t], hA[t]);  // global reservation (256/block)
    rB[t] = atomicAdd(&curB[t], hB[t]);
    __syncthreads();
    for (int i = t; i < cnt; i += 256) {
        int s = src[b0 + i], d = dst[b0 + i];
        int bd = d / BR;
        int bs = s / BR;
        int p = rA[bd] + atomicAdd(&cA[bd], 1);
        if (p < CAP) ppair[(size_t)bd * CAP + p] = make_uint2((uint)d, (uint)s);
        int q = rB[bs] + atomicAdd(&cB[bs], 1);
        if (q < CAP) psv[(size_t)bs * CAP + q] = s;
    }
}

// ---------------- pass 2: per-bucket CSR + rowstart + ndst + nsrc (LDS atomics only) ----------
// Includes the 256-wide exclusive scan of bucket counts (redundant per block, trivial cost).
__global__ __launch_bounds__(512) void csrn_kernel(const int* __restrict__ curA,
                                                   const int* __restrict__ curB,
                                                   const uint2* __restrict__ ppair,
                                                   const int* __restrict__ psv,
                                                   int* __restrict__ csr,
                                                   int* __restrict__ rowstart,
                                                   float* __restrict__ ndst,
                                                   float* __restrict__ nsrc, int n, int e) {
    __shared__ ushort dloc[CAP];  // 16KB
    __shared__ uint sloc[CAP];    // 32KB
    __shared__ int hist[512], sc[512], exc[512], cur[512];
    __shared__ int sbst;
    const int t = threadIdx.x;
    const int b = blockIdx.x;
    const int first = b * BR;
    const int nr = min(BR, n - first);
    const int cntA = min(curA[b], CAP);
    const size_t base = (size_t)b * CAP;

    // scan of 256 bucket counts -> this bucket's csr base
    if (t < 256) sc[t] = curA[t];
    __syncthreads();
    for (int off = 1; off < 256; off <<= 1) {
        int add = 0;
        if (t < 256 && t >= off) add = sc[t - off];
        __syncthreads();
        if (t < 256) sc[t] += add;
        __syncthreads();
    }
    if (t == 0) {
        sbst = (b == 0) ? 0 : sc[b - 1];
        if (b == 0) rowstart[n] = e;
    }
    hist[t] = 0;
    cur[t] = 0;
    __syncthreads();
    const int bst = sbst;

    for (int i = t; i < cntA; i += 512) {
        uint2 ed = ppair[base + i];
        int dl = (int)ed.x - first;
        dloc[i] = (ushort)dl;
        sloc[i] = ed.y;
        atomicAdd(&hist[dl], 1);
    }
    __syncthreads();
    int h = hist[t];
    sc[t] = h;
    __syncthreads();
    for (int off = 1; off < 512; off <<= 1) {
        int add = (t >= off) ? sc[t - off] : 0;
        __syncthreads();
        sc[t] += add;
        __syncthreads();
    }
    exc[t] = sc[t] - h;
    if (t < nr) {
        rowstart[first + t] = bst + exc[t];
        ndst[first + t] = rsqrtf(fmaxf((float)h, 1.0f));
    }
    __syncthreads();
    for (int i = t; i < cntA; i += 512) {
        int dl = dloc[i];
        int p = exc[dl] + atomicAdd(&cur[dl], 1);
        csr[bst + p] = (int)sloc[i];
    }

    // out-degree -> nsrc (src-bucketed partition)
    __syncthreads();
    hist[t] = 0;
    __syncthreads();
    const int cntB = min(curB[b], CAP);
    for (int i = t; i < cntB; i += 512) atomicAdd(&hist[psv[base + i] - first], 1);
    __syncthreads();
    if (t < nr) nsrc[first + t] = rsqrtf(fmaxf((float)hist[t], 1.0f));
}

// ---------------- fused prep: xb = bf16(x*nsrc) ; Wt1/Wt2 = bf16(W^T) ----------------
__global__ __launch_bounds__(256) void prep_kernel(const float* __restrict__ x,
                                                   const float* __restrict__ nsrc,
                                                   ushort* __restrict__ xb,
                                                   const float* __restrict__ W1,
                                                   ushort* __restrict__ Wt1,
                                                   const float* __restrict__ W2,
                                                   ushort* __restrict__ Wt2, int n) {
    const int nxb = (n * 32 + 255) / 256;  // xb blocks (quad-granular)
    int blk = blockIdx.x;
    if (blk < nxb) {
        int i = blk * 256 + threadIdx.x;
        if (i < n * 32) {
            int row = i >> 5;
            float s = nsrc[row];
            float4 v = *(const float4*)&x[(size_t)i * 4];
            ushort4 o = {f2bf(v.x * s), f2bf(v.y * s), f2bf(v.z * s), f2bf(v.w * s)};
            *(ushort4*)&xb[(size_t)i * 4] = o;
        }
    } else if (blk < nxb + DIN * DHID / 256) {
        int i = (blk - nxb) * 256 + threadIdx.x;
        int k = i / DHID, c = i - k * DHID;
        Wt1[(size_t)c * DIN + k] = f2bf(W1[i]);
    } else {
        int i = (blk - nxb - DIN * DHID / 256) * 256 + threadIdx.x;
        int k = i / DOUT, c = i - k * DOUT;
        Wt2[(size_t)c * DHID + k] = f2bf(W2[i]);
    }
}

// ---------------- bf16 gather-aggregate: 16 dst rows / block, uint4 (16B) per lane-of-16 -----
template <bool OUTBF16, bool ADDBIAS>
__global__ __launch_bounds__(256) void aggb_kernel(const ushort* __restrict__ Xb,
                                                   const int* __restrict__ csr,
                                                   const int* __restrict__ rowstart,
                                                   const float* __restrict__ ndst,
                                                   const float* __restrict__ bias,
                                                   float* __restrict__ outf,
                                                   ushort* __restrict__ outb, int n) {
    int g = threadIdx.x >> 4;     // 0..15 row group
    int lane = threadIdx.x & 15;  // feature group: bf16 [lane*8, lane*8+8) = 16B
    int d = blockIdx.x * 16 + g;
    if (d >= n) return;
    int beg = rowstart[d], end = rowstart[d + 1];
    const int fo = lane * 8;
    const ushort* Xp = Xb + fo;
    float acc[8];
#pragma unroll
    for (int j = 0; j < 8; j++) acc[j] = 0.f;

#define ACC8(v)                                 \
    do {                                        \
        acc[0] += bflo(v.x); acc[1] += bfhi(v.x); \
        acc[2] += bflo(v.y); acc[3] += bfhi(v.y); \
        acc[4] += bflo(v.z); acc[5] += bfhi(v.z); \
        acc[6] += bflo(v.w); acc[7] += bfhi(v.w); \
    } while (0)

    int k = beg;
    for (; k + 4 <= end; k += 4) {
        int s0 = csr[k], s1 = csr[k + 1], s2 = csr[k + 2], s3 = csr[k + 3];
        uint4 v0 = *(const uint4*)(Xp + (size_t)s0 * 128);
        uint4 v1 = *(const uint4*)(Xp + (size_t)s1 * 128);
        uint4 v2 = *(const uint4*)(Xp + (size_t)s2 * 128);
        uint4 v3 = *(const uint4*)(Xp + (size_t)s3 * 128);
        ACC8(v0);
        ACC8(v1);
        ACC8(v2);
        ACC8(v3);
    }
    for (; k < end; ++k) {
        uint4 v = *(const uint4*)(Xp + (size_t)csr[k] * 128);
        ACC8(v);
    }
#undef ACC8

    float nd = ndst[d];
#pragma unroll
    for (int j = 0; j < 8; j++) acc[j] *= nd;
    if constexpr (ADDBIAS) {
        float4 b0 = *(const float4*)&bias[fo];
        float4 b1 = *(const float4*)&bias[fo + 4];
        acc[0] += b0.x; acc[1] += b0.y; acc[2] += b0.z; acc[3] += b0.w;
        acc[4] += b1.x; acc[5] += b1.y; acc[6] += b1.z; acc[7] += b1.w;
    }
    if constexpr (OUTBF16) {
        uint4 o;
        o.x = (uint)f2bf(acc[0]) | ((uint)f2bf(acc[1]) << 16);
        o.y = (uint)f2bf(acc[2]) | ((uint)f2bf(acc[3]) << 16);
        o.z = (uint)f2bf(acc[4]) | ((uint)f2bf(acc[5]) << 16);
        o.w = (uint)f2bf(acc[6]) | ((uint)f2bf(acc[7]) << 16);
        *(uint4*)(outb + (size_t)d * 128 + fo) = o;
    } else {
        float4 o0 = {acc[0], acc[1], acc[2], acc[3]};
        float4 o1 = {acc[4], acc[5], acc[6], acc[7]};
        *(float4*)(outf + (size_t)d * 128 + fo) = o0;
        *(float4*)(outf + (size_t)d * 128 + fo + 4) = o1;
    }
}

// ---------------- pure-bf16 MFMA GEMM: C = epi(A @ B) as bf16 ----------------
// BM=BN=128, KB=32, 256 threads = 4 waves (2x2), wave = 64x64 = 4x4 frags of 16x16x32.
// LDS 16KB, group-of-8 XOR swizzle (g ^= (row>>2)&3) -> conflict-free b128 reads.
template <int K, int NOUT, bool EPI_RELU>
__global__ __launch_bounds__(256) void bgemm_kernel(const ushort* __restrict__ A,
                                                    const ushort* __restrict__ Bt,
                                                    const float* __restrict__ bias,
                                                    const float* __restrict__ rowscale,
                                                    ushort* __restrict__ C, int M) {
    constexpr int BM = 128, BN = 128, KB = 32, LDT = 32;
    __shared__ ushort As[BM][LDT], Bs[BN][LDT];
    const int row0 = blockIdx.x * BM, col0 = blockIdx.y * BN;
    const int t = threadIdx.x;
    const int wid = t >> 6, lane = t & 63;
    const int wr = wid >> 1, wc = wid & 1;
    const int l16 = lane & 15, lk = lane >> 4;
    const int sw = (l16 >> 2) & 3;  // read-side swizzle (row>>2)&3 for rows i*16+l16

    f32x4 acc[4][4];
#pragma unroll
    for (int i = 0; i < 4; i++)
#pragma unroll
        for (int j = 0; j < 4; j++) acc[i][j] = (f32x4){0.f, 0.f, 0.f, 0.f};

    for (int kb = 0; kb < K; kb += KB) {
#pragma unroll
        for (int i = 0; i < 2; i++) {
            int idx = i * 256 + t;          // 0..511 uint4-pieces
            int r = idx >> 2, s = idx & 3;  // row, k-octet
            int g = s ^ ((r >> 2) & 3);     // swizzled group
            int gr = row0 + r;
            uint4 v = make_uint4(0u, 0u, 0u, 0u);
            if (gr < M) v = *(const uint4*)&A[(size_t)gr * K + kb + s * 8];
            *(uint4*)&As[r][g * 8] = v;
            *(uint4*)&Bs[r][g * 8] = *(const uint4*)&Bt[(size_t)(col0 + r) * K + kb + s * 8];
        }
        __syncthreads();

        bf16x8 a[4], b[4];
#pragma unroll
        for (int i = 0; i < 4; i++) {
            a[i] = *(const bf16x8*)&As[wr * 64 + i * 16 + l16][(lk ^ sw) * 8];
            b[i] = *(const bf16x8*)&Bs[wc * 64 + i * 16 + l16][(lk ^ sw) * 8];
        }
#pragma unroll
        for (int i = 0; i < 4; i++)
#pragma unroll
            for (int j = 0; j < 4; j++)
                acc[i][j] = __builtin_amdgcn_mfma_f32_16x16x32_bf16(a[i], b[j], acc[i][j], 0, 0, 0);
        __syncthreads();
    }

    // C/D layout: col=lane&15, row=(lane>>4)*4+q  [m89/m91-verified]
#pragma unroll
    for (int i = 0; i < 4; i++) {
#pragma unroll
        for (int j = 0; j < 4; j++) {
#pragma unroll
            for (int q = 0; q < 4; q++) {
                int r = row0 + wr * 64 + i * 16 + lk * 4 + q;
                int c = col0 + wc * 64 + j * 16 + l16;
                if (r < M) {
                    float v = acc[i][j][q];
                    if constexpr (EPI_RELU) v = fmaxf(v + bias[c], 0.f) * rowscale[r];
                    C[(size_t)r * NOUT + c] = f2bf(v);
                }
            }
        }
    }
}

extern "C" void kernel_launch(void* const* d_in, const int* in_sizes, int n_in,
                              void* d_out, int out_size, void* d_ws, size_t ws_size,
                              hipStream_t stream) {
    const float* x  = (const float*)d_in[0];
    const int*   src = (const int*)d_in[1];
    const int*   dst = (const int*)d_in[2];
    const float* W1 = (const float*)d_in[3];
    const float* b1 = (const float*)d_in[4];
    const float* W2 = (const float*)d_in[5];
    const float* b2 = (const float*)d_in[6];
    float* out = (float*)d_out;

    const int N = N_NODES, E = N_EDGES;

    size_t off = 0;
    auto carve = [&](size_t bytes) -> void* {
        void* p = (char*)d_ws + off;
        off += (bytes + 255) & ~(size_t)255;
        return p;
    };
    int* curA     = (int*)carve(NB * 4);
    int* curB     = (int*)carve(NB * 4);
    int* rowstart = (int*)carve((size_t)(N + 1) * 4);
    float* ndst   = (float*)carve((size_t)N * 4);
    float* nsrc   = (float*)carve((size_t)N * 4);
    int* csr      = (int*)carve((size_t)E * 4);
    ushort* Wt1   = (ushort*)carve(DIN * DHID * 2);
    ushort* Wt2   = (ushort*)carve(DHID * DOUT * 2);
    ushort* xb    = (ushort*)carve((size_t)N * DIN * 2);   // bf16(x*nsrc)
    ushort* agg1b = (ushort*)carve((size_t)N * DIN * 2);   // bf16 aggregate (GEMM1 A)
    ushort* h1b   = (ushort*)carve((size_t)N * DHID * 2);  // bf16(relu(h1)*nsrc)
    ushort* tb    = (ushort*)carve((size_t)N * DOUT * 2);  // bf16(h1b @ W2)

    // bucket scratch aliases h1b (dead until GEMM1, which runs after csrn)
    uint2* ppair = (uint2*)h1b;                                // 256*8192*8 = 16.8 MB
    int*   psv   = (int*)((char*)h1b + (size_t)NB * CAP * 8);  // +8.4 MB (h1b = 51.2 MB)

    hipMemsetAsync(curA, 0, 2 * NB * 4, stream);

    part_kernel<<<NBLK1, 256, 0, stream>>>(src, dst, curA, curB, ppair, psv, E);
    csrn_kernel<<<NB, 512, 0, stream>>>(curA, curB, ppair, psv, csr, rowstart, ndst, nsrc, N, E);

    const int nxb = (N * 32 + 255) / 256;
    prep_kernel<<<nxb + DIN * DHID / 256 + DHID * DOUT / 256, 256, 0, stream>>>(
        x, nsrc, xb, W1, Wt1, W2, Wt2, N);

    // layer 1 aggregation: agg1b = bf16(ndst * segsum(xb[src]))
    aggb_kernel<true, false><<<(N + 15) / 16, 256, 0, stream>>>(xb, csr, rowstart, ndst, nullptr,
                                                                nullptr, agg1b, N);

    // GEMM1: h1b = bf16(relu(agg1b @ W1 + b1) * nsrc)
    dim3 g1((N + 127) / 128, DHID / 128);
    bgemm_kernel<DIN, DHID, true><<<g1, 256, 0, stream>>>(agg1b, Wt1, b1, nsrc, h1b, N);

    // GEMM2: tb = bf16(h1b @ W2)
    dim3 g2((N + 127) / 128, DOUT / 128);
    bgemm_kernel<DHID, DOUT, false><<<g2, 256, 0, stream>>>(h1b, Wt2, nullptr, nullptr, tb, N);

    // layer 2 aggregation: out = ndst * segsum(tb[src]) + b2
    aggb_kernel<false, true><<<(N + 15) / 16, 256, 0, stream>>>(tb, csr, rowstart, ndst, b2,
                                                                out, nullptr, N);
}

// Round 7
// 257.870 us; speedup vs baseline: 2.9089x; 1.0562x over previous
//
#include <hip/hip_runtime.h>

constexpr int N_NODES = 100000;
constexpr int N_EDGES = 1600000;
constexpr int DIN = 128, DHID = 256, DOUT = 128;

constexpr int NB = 256;    // buckets
constexpr int BR = 391;    // node range per bucket (256*391 = 100096 >= N)
constexpr int CAP = 8192;  // per-bucket capacity (mean 6250)
constexpr int NBLK1 = 512;
constexpr int CHUNK = (N_EDGES + NBLK1 - 1) / NBLK1;  // 3125

typedef __bf16 bf16x8 __attribute__((ext_vector_type(8)));
typedef float f32x4 __attribute__((ext_vector_type(4)));

static __device__ __forceinline__ ushort f2bf(float f) {
    uint u = __float_as_uint(f);
    uint r = (u + 0x7FFFu + ((u >> 16) & 1u)) >> 16;
    return (ushort)r;
}
static __device__ __forceinline__ float bf2f(ushort h) {
    return __uint_as_float(((uint)h) << 16);
}
static __device__ __forceinline__ float bflo(uint w) { return __uint_as_float(w << 16); }
static __device__ __forceinline__ float bfhi(uint w) { return __uint_as_float(w & 0xFFFF0000u); }

// ---------------- pass 1: partition edges into 256 buckets by dst/BR and src/BR ----------------
__global__ __launch_bounds__(256) void part_kernel(const int* __restrict__ src,
                                                   const int* __restrict__ dst,
                                                   int* __restrict__ curA, int* __restrict__ curB,
                                                   uint2* __restrict__ ppair,
                                                   int* __restrict__ psv, int e) {
    __shared__ int hA[NB], hB[NB], rA[NB], rB[NB], cA[NB], cB[NB];
    const int t = threadIdx.x;
    const int b0 = blockIdx.x * CHUNK;
    const int cnt = min(e - b0, CHUNK);
    hA[t] = 0; hB[t] = 0; cA[t] = 0; cB[t] = 0;
    __syncthreads();
    for (int i = t; i < cnt; i += 256) {
        int s = src[b0 + i], d = dst[b0 + i];
        atomicAdd(&hA[d / BR], 1);
        atomicAdd(&hB[s / BR], 1);
    }
    __syncthreads();
    rA[t] = atomicAdd(&curA[t], hA[t]);  // global reservation (256/block)
    rB[t] = atomicAdd(&curB[t], hB[t]);
    __syncthreads();
    for (int i = t; i < cnt; i += 256) {
        int s = src[b0 + i], d = dst[b0 + i];
        int bd = d / BR;
        int bs = s / BR;
        int p = rA[bd] + atomicAdd(&cA[bd], 1);
        if (p < CAP) ppair[(size_t)bd * CAP + p] = make_uint2((uint)d, (uint)s);
        int q = rB[bs] + atomicAdd(&cB[bs], 1);
        if (q < CAP) psv[(size_t)bs * CAP + q] = s;
    }
}

// ---------------- pass 2: per-bucket CSR + rowstart + ndst + nsrc (LDS atomics only) ----------
__global__ __launch_bounds__(512) void csrn_kernel(const int* __restrict__ curA,
                                                   const int* __restrict__ curB,
                                                   const uint2* __restrict__ ppair,
                                                   const int* __restrict__ psv,
                                                   int* __restrict__ csr,
                                                   int* __restrict__ rowstart,
                                                   float* __restrict__ ndst,
                                                   float* __restrict__ nsrc, int n, int e) {
    __shared__ ushort dloc[CAP];  // 16KB
    __shared__ uint sloc[CAP];    // 32KB
    __shared__ int hist[512], sc[512], exc[512], cur[512];
    __shared__ int sbst;
    const int t = threadIdx.x;
    const int b = blockIdx.x;
    const int first = b * BR;
    const int nr = min(BR, n - first);
    const int cntA = min(curA[b], CAP);
    const size_t base = (size_t)b * CAP;

    // scan of 256 bucket counts -> this bucket's csr base
    if (t < 256) sc[t] = curA[t];
    __syncthreads();
    for (int off = 1; off < 256; off <<= 1) {
        int add = 0;
        if (t < 256 && t >= off) add = sc[t - off];
        __syncthreads();
        if (t < 256) sc[t] += add;
        __syncthreads();
    }
    if (t == 0) {
        sbst = (b == 0) ? 0 : sc[b - 1];
        if (b == 0) rowstart[n] = e;
    }
    hist[t] = 0;
    cur[t] = 0;
    __syncthreads();
    const int bst = sbst;

    for (int i = t; i < cntA; i += 512) {
        uint2 ed = ppair[base + i];
        int dl = (int)ed.x - first;
        dloc[i] = (ushort)dl;
        sloc[i] = ed.y;
        atomicAdd(&hist[dl], 1);
    }
    __syncthreads();
    int h = hist[t];
    sc[t] = h;
    __syncthreads();
    for (int off = 1; off < 512; off <<= 1) {
        int add = (t >= off) ? sc[t - off] : 0;
        __syncthreads();
        sc[t] += add;
        __syncthreads();
    }
    exc[t] = sc[t] - h;
    if (t < nr) {
        rowstart[first + t] = bst + exc[t];
        ndst[first + t] = rsqrtf(fmaxf((float)h, 1.0f));
    }
    __syncthreads();
    for (int i = t; i < cntA; i += 512) {
        int dl = dloc[i];
        int p = exc[dl] + atomicAdd(&cur[dl], 1);
        csr[bst + p] = (int)sloc[i];
    }

    // out-degree -> nsrc (src-bucketed partition)
    __syncthreads();
    hist[t] = 0;
    __syncthreads();
    const int cntB = min(curB[b], CAP);
    for (int i = t; i < cntB; i += 512) atomicAdd(&hist[psv[base + i] - first], 1);
    __syncthreads();
    if (t < nr) nsrc[first + t] = rsqrtf(fmaxf((float)hist[t], 1.0f));
}

// ---------------- fused prep: xb = bf16(x*nsrc) ; Wt1/Wt2 = bf16(W^T) ----------------
__global__ __launch_bounds__(256) void prep_kernel(const float* __restrict__ x,
                                                   const float* __restrict__ nsrc,
                                                   ushort* __restrict__ xb,
                                                   const float* __restrict__ W1,
                                                   ushort* __restrict__ Wt1,
                                                   const float* __restrict__ W2,
                                                   ushort* __restrict__ Wt2, int n) {
    const int nxb = (n * 32 + 255) / 256;  // xb blocks (quad-granular)
    int blk = blockIdx.x;
    if (blk < nxb) {
        int i = blk * 256 + threadIdx.x;
        if (i < n * 32) {
            int row = i >> 5;
            float s = nsrc[row];
            float4 v = *(const float4*)&x[(size_t)i * 4];
            ushort4 o = {f2bf(v.x * s), f2bf(v.y * s), f2bf(v.z * s), f2bf(v.w * s)};
            *(ushort4*)&xb[(size_t)i * 4] = o;
        }
    } else if (blk < nxb + DIN * DHID / 256) {
        int i = (blk - nxb) * 256 + threadIdx.x;
        int k = i / DHID, c = i - k * DHID;
        Wt1[(size_t)c * DIN + k] = f2bf(W1[i]);
    } else {
        int i = (blk - nxb - DIN * DHID / 256) * 256 + threadIdx.x;
        int k = i / DOUT, c = i - k * DOUT;
        Wt2[(size_t)c * DHID + k] = f2bf(W2[i]);
    }
}

// ---------------- bf16 gather-aggregate: 16 dst rows / block, uint4 (16B) per lane-of-16 -----
template <bool OUTBF16, bool ADDBIAS>
__global__ __launch_bounds__(256) void aggb_kernel(const ushort* __restrict__ Xb,
                                                   const int* __restrict__ csr,
                                                   const int* __restrict__ rowstart,
                                                   const float* __restrict__ ndst,
                                                   const float* __restrict__ bias,
                                                   float* __restrict__ outf,
                                                   ushort* __restrict__ outb, int n) {
    int g = threadIdx.x >> 4;     // 0..15 row group
    int lane = threadIdx.x & 15;  // feature group: bf16 [lane*8, lane*8+8) = 16B
    int d = blockIdx.x * 16 + g;
    if (d >= n) return;
    int beg = rowstart[d], end = rowstart[d + 1];
    const int fo = lane * 8;
    const ushort* Xp = Xb + fo;
    float acc[8];
#pragma unroll
    for (int j = 0; j < 8; j++) acc[j] = 0.f;

#define ACC8(v)                                 \
    do {                                        \
        acc[0] += bflo(v.x); acc[1] += bfhi(v.x); \
        acc[2] += bflo(v.y); acc[3] += bfhi(v.y); \
        acc[4] += bflo(v.z); acc[5] += bfhi(v.z); \
        acc[6] += bflo(v.w); acc[7] += bfhi(v.w); \
    } while (0)

    int k = beg;
    for (; k + 4 <= end; k += 4) {
        int s0 = csr[k], s1 = csr[k + 1], s2 = csr[k + 2], s3 = csr[k + 3];
        uint4 v0 = *(const uint4*)(Xp + (size_t)s0 * 128);
        uint4 v1 = *(const uint4*)(Xp + (size_t)s1 * 128);
        uint4 v2 = *(const uint4*)(Xp + (size_t)s2 * 128);
        uint4 v3 = *(const uint4*)(Xp + (size_t)s3 * 128);
        ACC8(v0);
        ACC8(v1);
        ACC8(v2);
        ACC8(v3);
    }
    for (; k < end; ++k) {
        uint4 v = *(const uint4*)(Xp + (size_t)csr[k] * 128);
        ACC8(v);
    }
#undef ACC8

    float nd = ndst[d];
#pragma unroll
    for (int j = 0; j < 8; j++) acc[j] *= nd;
    if constexpr (ADDBIAS) {
        float4 b0 = *(const float4*)&bias[fo];
        float4 b1 = *(const float4*)&bias[fo + 4];
        acc[0] += b0.x; acc[1] += b0.y; acc[2] += b0.z; acc[3] += b0.w;
        acc[4] += b1.x; acc[5] += b1.y; acc[6] += b1.z; acc[7] += b1.w;
    }
    if constexpr (OUTBF16) {
        uint4 o;
        o.x = (uint)f2bf(acc[0]) | ((uint)f2bf(acc[1]) << 16);
        o.y = (uint)f2bf(acc[2]) | ((uint)f2bf(acc[3]) << 16);
        o.z = (uint)f2bf(acc[4]) | ((uint)f2bf(acc[5]) << 16);
        o.w = (uint)f2bf(acc[6]) | ((uint)f2bf(acc[7]) << 16);
        *(uint4*)(outb + (size_t)d * 128 + fo) = o;
    } else {
        float4 o0 = {acc[0], acc[1], acc[2], acc[3]};
        float4 o1 = {acc[4], acc[5], acc[6], acc[7]};
        *(float4*)(outf + (size_t)d * 128 + fo) = o0;
        *(float4*)(outf + (size_t)d * 128 + fo + 4) = o1;
    }
}

// ---------------- fused GEMM1+GEMM2 ----------------
// Per 128-row tile: H = relu(A @ W1 + b1) * nsrc  (H^T via swapped-operand MFMA, per 128-col
// half kh), H staged bf16 in LDS (4-bit XOR swizzle), then T += H_half @ W2_half.
// h1 intermediate never touches global memory.
__global__ __launch_bounds__(256) void fused_kernel(const ushort* __restrict__ A,
                                                    const ushort* __restrict__ Wt1,
                                                    const float* __restrict__ b1,
                                                    const float* __restrict__ nsrc,
                                                    const ushort* __restrict__ Wt2,
                                                    ushort* __restrict__ T, int M) {
    __shared__ ushort Sa[128][32];   // A rows (m,k) tile            8 KB
    __shared__ ushort Sb[128][32];   // W1-col / W2-col tile         8 KB
    __shared__ ushort H1[128][128];  // H half [m][c_local], swizzled 32 KB
    const int row0 = blockIdx.x * 128;
    const int t = threadIdx.x;
    const int wid = t >> 6, lane = t & 63;
    const int wr = wid >> 1, wc = wid & 1;
    const int l16 = lane & 15, lk = lane >> 4;
    const int sw = (l16 >> 2) & 3;

    f32x4 acc2[4][4];
#pragma unroll
    for (int i = 0; i < 4; i++)
#pragma unroll
        for (int j = 0; j < 4; j++) acc2[i][j] = (f32x4){0.f, 0.f, 0.f, 0.f};

    for (int kh = 0; kh < 2; kh++) {
        // ---- Phase B: acc1 = (A @ W1half)^T  (A-op = W1^T, B-op = A^T) ----
        f32x4 acc1[4][4];
#pragma unroll
        for (int i = 0; i < 4; i++)
#pragma unroll
            for (int j = 0; j < 4; j++) acc1[i][j] = (f32x4){0.f, 0.f, 0.f, 0.f};

        for (int kb = 0; kb < DIN; kb += 32) {
#pragma unroll
            for (int i = 0; i < 2; i++) {
                int idx = i * 256 + t;
                int r = idx >> 2, s = idx & 3;
                int g = s ^ ((r >> 2) & 3);
                int gr = row0 + r;
                uint4 va = make_uint4(0u, 0u, 0u, 0u);
                if (gr < M) va = *(const uint4*)&A[(size_t)gr * DIN + kb + s * 8];
                *(uint4*)&Sa[r][g * 8] = va;
                *(uint4*)&Sb[r][g * 8] =
                    *(const uint4*)&Wt1[(size_t)(kh * 128 + r) * DIN + kb + s * 8];
            }
            __syncthreads();
            bf16x8 af[4], bf_[4];
#pragma unroll
            for (int i = 0; i < 4; i++) {
                af[i] = *(const bf16x8*)&Sb[wr * 64 + i * 16 + l16][(lk ^ sw) * 8];
                bf_[i] = *(const bf16x8*)&Sa[wc * 64 + i * 16 + l16][(lk ^ sw) * 8];
            }
#pragma unroll
            for (int i = 0; i < 4; i++)
#pragma unroll
                for (int j = 0; j < 4; j++)
                    acc1[i][j] =
                        __builtin_amdgcn_mfma_f32_16x16x32_bf16(af[i], bf_[j], acc1[i][j], 0, 0, 0);
            __syncthreads();
        }

        // ---- epilogue: lane holds D[c_local=wr*64+i*16+lk*4+q][m=wc*64+j*16+l16] ----
        // H1[m][c] with c-octet swizzle: oct' = oct ^ (m & 15)  -> conflict-free b64 writes
#pragma unroll
        for (int i = 0; i < 4; i++) {
            int cb = wr * 64 + i * 16 + lk * 4;  // c_local base, q = 0..3
            float4 bv = *(const float4*)&b1[kh * 128 + cb];
#pragma unroll
            for (int j = 0; j < 4; j++) {
                int m = wc * 64 + j * 16 + l16;
                int gm = row0 + m;
                float ns = nsrc[gm < M ? gm : (M - 1)];
                ushort4 pk;
                pk.x = f2bf(fmaxf(acc1[i][j][0] + bv.x, 0.f) * ns);
                pk.y = f2bf(fmaxf(acc1[i][j][1] + bv.y, 0.f) * ns);
                pk.z = f2bf(fmaxf(acc1[i][j][2] + bv.z, 0.f) * ns);
                pk.w = f2bf(fmaxf(acc1[i][j][3] + bv.w, 0.f) * ns);
                int octp = (cb >> 3) ^ (m & 15);
                *(ushort4*)((char*)&H1[0][0] + m * 256 + octp * 16 + (cb & 7) * 2) = pk;
            }
        }
        __syncthreads();

        // ---- Phase D: acc2 += H1(128 x 128k) @ W2[kh*128 .. +128][:] ----
        for (int kb2 = 0; kb2 < 128; kb2 += 32) {
#pragma unroll
            for (int i = 0; i < 2; i++) {
                int idx = i * 256 + t;
                int r = idx >> 2, s = idx & 3;
                int g = s ^ ((r >> 2) & 3);
                *(uint4*)&Sb[r][g * 8] =
                    *(const uint4*)&Wt2[(size_t)r * DHID + kh * 128 + kb2 + s * 8];
            }
            __syncthreads();
            bf16x8 ha[4], wb[4];
#pragma unroll
            for (int i = 0; i < 4; i++) {
                int m2 = wr * 64 + i * 16 + l16;  // (m2 & 15) == l16
                int octp = ((kb2 >> 3) + lk) ^ l16;
                ha[i] = *(const bf16x8*)((const char*)&H1[0][0] + m2 * 256 + octp * 16);
                wb[i] = *(const bf16x8*)&Sb[wc * 64 + i * 16 + l16][(lk ^ sw) * 8];
            }
#pragma unroll
            for (int i = 0; i < 4; i++)
#pragma unroll
                for (int j = 0; j < 4; j++)
                    acc2[i][j] =
                        __builtin_amdgcn_mfma_f32_16x16x32_bf16(ha[i], wb[j], acc2[i][j], 0, 0, 0);
            __syncthreads();
        }
    }

    // ---- write T: C/D layout col=lane&15, row=(lane>>4)*4+q ----
#pragma unroll
    for (int i = 0; i < 4; i++) {
#pragma unroll
        for (int j = 0; j < 4; j++) {
#pragma unroll
            for (int q = 0; q < 4; q++) {
                int r = row0 + wr * 64 + i * 16 + lk * 4 + q;
                int c = wc * 64 + j * 16 + l16;
                if (r < M) T[(size_t)r * DOUT + c] = f2bf(acc2[i][j][q]);
            }
        }
    }
}

extern "C" void kernel_launch(void* const* d_in, const int* in_sizes, int n_in,
                              void* d_out, int out_size, void* d_ws, size_t ws_size,
                              hipStream_t stream) {
    const float* x  = (const float*)d_in[0];
    const int*   src = (const int*)d_in[1];
    const int*   dst = (const int*)d_in[2];
    const float* W1 = (const float*)d_in[3];
    const float* b1 = (const float*)d_in[4];
    const float* W2 = (const float*)d_in[5];
    const float* b2 = (const float*)d_in[6];
    float* out = (float*)d_out;

    const int N = N_NODES, E = N_EDGES;

    size_t off = 0;
    auto carve = [&](size_t bytes) -> void* {
        void* p = (char*)d_ws + off;
        off += (bytes + 255) & ~(size_t)255;
        return p;
    };
    int* curA     = (int*)carve(NB * 4);
    int* curB     = (int*)carve(NB * 4);
    int* rowstart = (int*)carve((size_t)(N + 1) * 4);
    float* ndst   = (float*)carve((size_t)N * 4);
    float* nsrc   = (float*)carve((size_t)N * 4);
    int* csr      = (int*)carve((size_t)E * 4);
    ushort* Wt1   = (ushort*)carve(DIN * DHID * 2);
    ushort* Wt2   = (ushort*)carve(DHID * DOUT * 2);
    ushort* xb    = (ushort*)carve((size_t)N * DIN * 2);   // bf16(x*nsrc)
    ushort* agg1b = (ushort*)carve((size_t)N * DIN * 2);   // bf16 aggregate (fused A)
    ushort* tb    = (ushort*)carve((size_t)N * DOUT * 2);  // bf16 fused output
    uint2* ppair  = (uint2*)carve((size_t)NB * CAP * 8);   // bucket scratch 16.8 MB
    int*   psv    = (int*)carve((size_t)NB * CAP * 4);     // bucket scratch 8.4 MB

    hipMemsetAsync(curA, 0, 2 * NB * 4, stream);

    part_kernel<<<NBLK1, 256, 0, stream>>>(src, dst, curA, curB, ppair, psv, E);
    csrn_kernel<<<NB, 512, 0, stream>>>(curA, curB, ppair, psv, csr, rowstart, ndst, nsrc, N, E);

    const int nxb = (N * 32 + 255) / 256;
    prep_kernel<<<nxb + DIN * DHID / 256 + DHID * DOUT / 256, 256, 0, stream>>>(
        x, nsrc, xb, W1, Wt1, W2, Wt2, N);

    // layer 1 aggregation: agg1b = bf16(ndst * segsum(xb[src]))
    aggb_kernel<true, false><<<(N + 15) / 16, 256, 0, stream>>>(xb, csr, rowstart, ndst, nullptr,
                                                                nullptr, agg1b, N);

    // fused GEMM1+GEMM2: tb = bf16( (relu(agg1b @ W1 + b1) * nsrc) @ W2 )
    fused_kernel<<<(N + 127) / 128, 256, 0, stream>>>(agg1b, Wt1, b1, nsrc, Wt2, tb, N);

    // layer 2 aggregation: out = ndst * segsum(tb[src]) + b2
    aggb_kernel<false, true><<<(N + 15) / 16, 256, 0, stream>>>(tb, csr, rowstart, ndst, b2,
                                                                out, nullptr, N);
}

// Round 8
// 240.091 us; speedup vs baseline: 3.1243x; 1.0741x over previous
//
#include <hip/hip_runtime.h>

constexpr int N_NODES = 100000;
constexpr int N_EDGES = 1600000;
constexpr int DIN = 128, DHID = 256, DOUT = 128;

constexpr int NB = 256;    // buckets
constexpr int BR = 391;    // node range per bucket (256*391 = 100096 >= N)
constexpr int CAP = 8192;  // per-bucket capacity (mean 6250)
constexpr int NBLK1 = 512;
constexpr int CHUNK = (N_EDGES + NBLK1 - 1) / NBLK1;  // 3125

typedef __bf16 bf16x8 __attribute__((ext_vector_type(8)));
typedef float f32x4 __attribute__((ext_vector_type(4)));

static __device__ __forceinline__ ushort f2bf(float f) {
    uint u = __float_as_uint(f);
    uint r = (u + 0x7FFFu + ((u >> 16) & 1u)) >> 16;
    return (ushort)r;
}
static __device__ __forceinline__ float bf2f(ushort h) {
    return __uint_as_float(((uint)h) << 16);
}
static __device__ __forceinline__ float bflo(uint w) { return __uint_as_float(w << 16); }
static __device__ __forceinline__ float bfhi(uint w) { return __uint_as_float(w & 0xFFFF0000u); }

// ---------------- pass 1: partition edges into 256 buckets by dst/BR and src/BR ----------------
__global__ __launch_bounds__(256) void part_kernel(const int* __restrict__ src,
                                                   const int* __restrict__ dst,
                                                   int* __restrict__ curA, int* __restrict__ curB,
                                                   uint2* __restrict__ ppair,
                                                   int* __restrict__ psv, int e) {
    __shared__ int hA[NB], hB[NB], rA[NB], rB[NB], cA[NB], cB[NB];
    const int t = threadIdx.x;
    const int b0 = blockIdx.x * CHUNK;
    const int cnt = min(e - b0, CHUNK);
    hA[t] = 0; hB[t] = 0; cA[t] = 0; cB[t] = 0;
    __syncthreads();
    for (int i = t; i < cnt; i += 256) {
        int s = src[b0 + i], d = dst[b0 + i];
        atomicAdd(&hA[d / BR], 1);
        atomicAdd(&hB[s / BR], 1);
    }
    __syncthreads();
    rA[t] = atomicAdd(&curA[t], hA[t]);  // global reservation (256/block)
    rB[t] = atomicAdd(&curB[t], hB[t]);
    __syncthreads();
    for (int i = t; i < cnt; i += 256) {
        int s = src[b0 + i], d = dst[b0 + i];
        int bd = d / BR;
        int bs = s / BR;
        int p = rA[bd] + atomicAdd(&cA[bd], 1);
        if (p < CAP) ppair[(size_t)bd * CAP + p] = make_uint2((uint)d, (uint)s);
        int q = rB[bs] + atomicAdd(&cB[bs], 1);
        if (q < CAP) psv[(size_t)bs * CAP + q] = s;
    }
}

// ---------------- pass 2: per-bucket CSR + rowstart + ndst + nsrc (LDS atomics only) ----------
__global__ __launch_bounds__(512) void csrn_kernel(const int* __restrict__ curA,
                                                   const int* __restrict__ curB,
                                                   const uint2* __restrict__ ppair,
                                                   const int* __restrict__ psv,
                                                   int* __restrict__ csr,
                                                   int* __restrict__ rowstart,
                                                   float* __restrict__ ndst,
                                                   float* __restrict__ nsrc, int n, int e) {
    __shared__ ushort dloc[CAP];  // 16KB
    __shared__ uint sloc[CAP];    // 32KB
    __shared__ int hist[512], sc[512], exc[512], cur[512];
    __shared__ int sbst;
    const int t = threadIdx.x;
    const int b = blockIdx.x;
    const int first = b * BR;
    const int nr = min(BR, n - first);
    const int cntA = min(curA[b], CAP);
    const size_t base = (size_t)b * CAP;

    // scan of 256 bucket counts -> this bucket's csr base
    if (t < 256) sc[t] = curA[t];
    __syncthreads();
    for (int off = 1; off < 256; off <<= 1) {
        int add = 0;
        if (t < 256 && t >= off) add = sc[t - off];
        __syncthreads();
        if (t < 256) sc[t] += add;
        __syncthreads();
    }
    if (t == 0) {
        sbst = (b == 0) ? 0 : sc[b - 1];
        if (b == 0) rowstart[n] = e;
    }
    hist[t] = 0;
    cur[t] = 0;
    __syncthreads();
    const int bst = sbst;

    for (int i = t; i < cntA; i += 512) {
        uint2 ed = ppair[base + i];
        int dl = (int)ed.x - first;
        dloc[i] = (ushort)dl;
        sloc[i] = ed.y;
        atomicAdd(&hist[dl], 1);
    }
    __syncthreads();
    int h = hist[t];
    sc[t] = h;
    __syncthreads();
    for (int off = 1; off < 512; off <<= 1) {
        int add = (t >= off) ? sc[t - off] : 0;
        __syncthreads();
        sc[t] += add;
        __syncthreads();
    }
    exc[t] = sc[t] - h;
    if (t < nr) {
        rowstart[first + t] = bst + exc[t];
        ndst[first + t] = rsqrtf(fmaxf((float)h, 1.0f));
    }
    __syncthreads();
    for (int i = t; i < cntA; i += 512) {
        int dl = dloc[i];
        int p = exc[dl] + atomicAdd(&cur[dl], 1);
        csr[bst + p] = (int)sloc[i];
    }

    // out-degree -> nsrc (src-bucketed partition)
    __syncthreads();
    hist[t] = 0;
    __syncthreads();
    const int cntB = min(curB[b], CAP);
    for (int i = t; i < cntB; i += 512) atomicAdd(&hist[psv[base + i] - first], 1);
    __syncthreads();
    if (t < nr) nsrc[first + t] = rsqrtf(fmaxf((float)hist[t], 1.0f));
}

// ---------------- fused prep: xb = bf16(x*nsrc) ; Wt1/Wt2 = bf16(W^T) ----------------
__global__ __launch_bounds__(256) void prep_kernel(const float* __restrict__ x,
                                                   const float* __restrict__ nsrc,
                                                   ushort* __restrict__ xb,
                                                   const float* __restrict__ W1,
                                                   ushort* __restrict__ Wt1,
                                                   const float* __restrict__ W2,
                                                   ushort* __restrict__ Wt2, int n) {
    const int nxb = (n * 32 + 255) / 256;  // xb blocks (quad-granular)
    int blk = blockIdx.x;
    if (blk < nxb) {
        int i = blk * 256 + threadIdx.x;
        if (i < n * 32) {
            int row = i >> 5;
            float s = nsrc[row];
            float4 v = *(const float4*)&x[(size_t)i * 4];
            ushort4 o = {f2bf(v.x * s), f2bf(v.y * s), f2bf(v.z * s), f2bf(v.w * s)};
            *(ushort4*)&xb[(size_t)i * 4] = o;
        }
    } else if (blk < nxb + DIN * DHID / 256) {
        int i = (blk - nxb) * 256 + threadIdx.x;
        int k = i / DHID, c = i - k * DHID;
        Wt1[(size_t)c * DIN + k] = f2bf(W1[i]);
    } else {
        int i = (blk - nxb - DIN * DHID / 256) * 256 + threadIdx.x;
        int k = i / DOUT, c = i - k * DOUT;
        Wt2[(size_t)c * DHID + k] = f2bf(W2[i]);
    }
}

// ---------------- bf16 gather-aggregate: 16 dst rows / block, uint4 (16B) per lane-of-16 -----
template <bool OUTBF16, bool ADDBIAS>
__global__ __launch_bounds__(256) void aggb_kernel(const ushort* __restrict__ Xb,
                                                   const int* __restrict__ csr,
                                                   const int* __restrict__ rowstart,
                                                   const float* __restrict__ ndst,
                                                   const float* __restrict__ bias,
                                                   float* __restrict__ outf,
                                                   ushort* __restrict__ outb, int n) {
    int g = threadIdx.x >> 4;     // 0..15 row group
    int lane = threadIdx.x & 15;  // feature group: bf16 [lane*8, lane*8+8) = 16B
    int d = blockIdx.x * 16 + g;
    if (d >= n) return;
    int beg = rowstart[d], end = rowstart[d + 1];
    const int fo = lane * 8;
    const ushort* Xp = Xb + fo;
    float acc[8];
#pragma unroll
    for (int j = 0; j < 8; j++) acc[j] = 0.f;

#define ACC8(v)                                 \
    do {                                        \
        acc[0] += bflo(v.x); acc[1] += bfhi(v.x); \
        acc[2] += bflo(v.y); acc[3] += bfhi(v.y); \
        acc[4] += bflo(v.z); acc[5] += bfhi(v.z); \
        acc[6] += bflo(v.w); acc[7] += bfhi(v.w); \
    } while (0)

    int k = beg;
    for (; k + 4 <= end; k += 4) {
        int s0 = csr[k], s1 = csr[k + 1], s2 = csr[k + 2], s3 = csr[k + 3];
        uint4 v0 = *(const uint4*)(Xp + (size_t)s0 * 128);
        uint4 v1 = *(const uint4*)(Xp + (size_t)s1 * 128);
        uint4 v2 = *(const uint4*)(Xp + (size_t)s2 * 128);
        uint4 v3 = *(const uint4*)(Xp + (size_t)s3 * 128);
        ACC8(v0);
        ACC8(v1);
        ACC8(v2);
        ACC8(v3);
    }
    for (; k < end; ++k) {
        uint4 v = *(const uint4*)(Xp + (size_t)csr[k] * 128);
        ACC8(v);
    }
#undef ACC8

    float nd = ndst[d];
#pragma unroll
    for (int j = 0; j < 8; j++) acc[j] *= nd;
    if constexpr (ADDBIAS) {
        float4 b0 = *(const float4*)&bias[fo];
        float4 b1 = *(const float4*)&bias[fo + 4];
        acc[0] += b0.x; acc[1] += b0.y; acc[2] += b0.z; acc[3] += b0.w;
        acc[4] += b1.x; acc[5] += b1.y; acc[6] += b1.z; acc[7] += b1.w;
    }
    if constexpr (OUTBF16) {
        uint4 o;
        o.x = (uint)f2bf(acc[0]) | ((uint)f2bf(acc[1]) << 16);
        o.y = (uint)f2bf(acc[2]) | ((uint)f2bf(acc[3]) << 16);
        o.z = (uint)f2bf(acc[4]) | ((uint)f2bf(acc[5]) << 16);
        o.w = (uint)f2bf(acc[6]) | ((uint)f2bf(acc[7]) << 16);
        *(uint4*)(outb + (size_t)d * 128 + fo) = o;
    } else {
        float4 o0 = {acc[0], acc[1], acc[2], acc[3]};
        float4 o1 = {acc[4], acc[5], acc[6], acc[7]};
        *(float4*)(outf + (size_t)d * 128 + fo) = o0;
        *(float4*)(outf + (size_t)d * 128 + fo + 4) = o1;
    }
}

// ---------------- fused GEMM1+GEMM2, BM=64, weights direct from global ----------------
// Per 64-row tile: Sa = A tile (staged once). Per kh half: H^T = W1h^T-frags (global) x
// A^T-frags (LDS) via swapped MFMA -> relu/bias/nsrc -> H1 (LDS, bf16, XOR-swizzled) ->
// acc2 += H1 @ W2h (W2 frags direct from global). Only 5 barriers per block.
__global__ __launch_bounds__(256) void fused64_kernel(const ushort* __restrict__ A,
                                                      const ushort* __restrict__ Wt1,
                                                      const float* __restrict__ b1,
                                                      const float* __restrict__ nsrc,
                                                      const ushort* __restrict__ Wt2,
                                                      ushort* __restrict__ T, int M) {
    __shared__ ushort Sa[64][128];  // A tile [m][k], oct' = oct ^ (m&15)   16 KB
    __shared__ ushort H1[64][128];  // H half [m][c], same swizzle          16 KB
    const int row0 = blockIdx.x * 64;
    const int t = threadIdx.x;
    const int w = t >> 6, lane = t & 63;
    const int l16 = lane & 15, lk = lane >> 4;

    // ---- stage A tile once (64 rows x 128 k) ----
#pragma unroll
    for (int i = 0; i < 4; i++) {
        int idx = i * 256 + t;  // 1024 uint4 pieces
        int r = idx >> 4, oct = idx & 15;
        int gr = row0 + r;
        uint4 v = make_uint4(0u, 0u, 0u, 0u);
        if (gr < M) v = *(const uint4*)&A[(size_t)gr * 128 + oct * 8];
        *(uint4*)((char*)&Sa[0][0] + r * 256 + (oct ^ (r & 15)) * 16) = v;
    }
    __syncthreads();

    f32x4 acc2[4][2];
#pragma unroll
    for (int i = 0; i < 4; i++)
#pragma unroll
        for (int j = 0; j < 2; j++) acc2[i][j] = (f32x4){0.f, 0.f, 0.f, 0.f};

    for (int kh = 0; kh < 2; kh++) {
        // ---- phase B: acc1 = (A @ W1half)^T ; wave w owns c-rows [w*32, w*32+32) ----
        f32x4 acc1[2][4];
#pragma unroll
        for (int i = 0; i < 2; i++)
#pragma unroll
            for (int j = 0; j < 4; j++) acc1[i][j] = (f32x4){0.f, 0.f, 0.f, 0.f};

        bf16x8 af[2][4];  // W1^T fragments, direct from global (prefetched)
#pragma unroll
        for (int i = 0; i < 2; i++)
#pragma unroll
            for (int kb = 0; kb < 4; kb++) {
                int c = w * 32 + i * 16 + l16;
                af[i][kb] =
                    *(const bf16x8*)&Wt1[(size_t)(kh * 128 + c) * 128 + kb * 32 + lk * 8];
            }
#pragma unroll
        for (int kb = 0; kb < 4; kb++) {
            bf16x8 bf_[4];
#pragma unroll
            for (int j = 0; j < 4; j++) {
                int m = j * 16 + l16;
                bf_[j] = *(const bf16x8*)((const char*)&Sa[0][0] + m * 256 +
                                          ((kb * 4 + lk) ^ l16) * 16);
            }
#pragma unroll
            for (int i = 0; i < 2; i++)
#pragma unroll
                for (int j = 0; j < 4; j++)
                    acc1[i][j] =
                        __builtin_amdgcn_mfma_f32_16x16x32_bf16(af[i][kb], bf_[j], acc1[i][j], 0, 0, 0);
        }
        __syncthreads();  // prior phase-D H1 reads done before overwrite

        // ---- epilogue: lane holds D[c = w*32+i*16+lk*4+q][m = j*16+l16] -> H1 ----
#pragma unroll
        for (int i = 0; i < 2; i++) {
            int cb = w * 32 + i * 16 + lk * 4;
            float4 bv = *(const float4*)&b1[kh * 128 + cb];
#pragma unroll
            for (int j = 0; j < 4; j++) {
                int m = j * 16 + l16;
                int gm = row0 + m;
                float ns = nsrc[gm < M ? gm : (M - 1)];
                ushort4 pk;
                pk.x = f2bf(fmaxf(acc1[i][j][0] + bv.x, 0.f) * ns);
                pk.y = f2bf(fmaxf(acc1[i][j][1] + bv.y, 0.f) * ns);
                pk.z = f2bf(fmaxf(acc1[i][j][2] + bv.z, 0.f) * ns);
                pk.w = f2bf(fmaxf(acc1[i][j][3] + bv.w, 0.f) * ns);
                int oct = cb >> 3;
                *(ushort4*)((char*)&H1[0][0] + m * 256 + ((oct ^ l16) & 15) * 16 +
                            (cb & 7) * 2) = pk;
            }
        }
        __syncthreads();  // H1 visible

        // ---- phase D: acc2 += H1 @ W2half ; wave w owns T-cols [w*32, w*32+32) ----
        bf16x8 wb[2][4];  // W2 fragments, direct from global (prefetched)
#pragma unroll
        for (int j2 = 0; j2 < 2; j2++)
#pragma unroll
            for (int kb2 = 0; kb2 < 4; kb2++) {
                int c2 = w * 32 + j2 * 16 + l16;
                wb[j2][kb2] =
                    *(const bf16x8*)&Wt2[(size_t)c2 * 256 + kh * 128 + kb2 * 32 + lk * 8];
            }
#pragma unroll
        for (int kb2 = 0; kb2 < 4; kb2++) {
            bf16x8 ha[4];
#pragma unroll
            for (int i2 = 0; i2 < 4; i2++) {
                int m = i2 * 16 + l16;
                ha[i2] = *(const bf16x8*)((const char*)&H1[0][0] + m * 256 +
                                          ((kb2 * 4 + lk) ^ l16) * 16);
            }
#pragma unroll
            for (int i2 = 0; i2 < 4; i2++)
#pragma unroll
                for (int j2 = 0; j2 < 2; j2++)
                    acc2[i2][j2] = __builtin_amdgcn_mfma_f32_16x16x32_bf16(ha[i2], wb[j2][kb2],
                                                                           acc2[i2][j2], 0, 0, 0);
        }
    }

    // ---- write T: C/D layout col=lane&15, row=(lane>>4)*4+q ----
#pragma unroll
    for (int i2 = 0; i2 < 4; i2++) {
#pragma unroll
        for (int j2 = 0; j2 < 2; j2++) {
#pragma unroll
            for (int q = 0; q < 4; q++) {
                int r = row0 + i2 * 16 + lk * 4 + q;
                int c = w * 32 + j2 * 16 + l16;
                if (r < M) T[(size_t)r * DOUT + c] = f2bf(acc2[i2][j2][q]);
            }
        }
    }
}

extern "C" void kernel_launch(void* const* d_in, const int* in_sizes, int n_in,
                              void* d_out, int out_size, void* d_ws, size_t ws_size,
                              hipStream_t stream) {
    const float* x  = (const float*)d_in[0];
    const int*   src = (const int*)d_in[1];
    const int*   dst = (const int*)d_in[2];
    const float* W1 = (const float*)d_in[3];
    const float* b1 = (const float*)d_in[4];
    const float* W2 = (const float*)d_in[5];
    const float* b2 = (const float*)d_in[6];
    float* out = (float*)d_out;

    const int N = N_NODES, E = N_EDGES;

    size_t off = 0;
    auto carve = [&](size_t bytes) -> void* {
        void* p = (char*)d_ws + off;
        off += (bytes + 255) & ~(size_t)255;
        return p;
    };
    int* curA     = (int*)carve(NB * 4);
    int* curB     = (int*)carve(NB * 4);
    int* rowstart = (int*)carve((size_t)(N + 1) * 4);
    float* ndst   = (float*)carve((size_t)N * 4);
    float* nsrc   = (float*)carve((size_t)N * 4);
    int* csr      = (int*)carve((size_t)E * 4);
    ushort* Wt1   = (ushort*)carve(DIN * DHID * 2);
    ushort* Wt2   = (ushort*)carve(DHID * DOUT * 2);
    ushort* xb    = (ushort*)carve((size_t)N * DIN * 2);   // bf16(x*nsrc)
    ushort* agg1b = (ushort*)carve((size_t)N * DIN * 2);   // bf16 aggregate (fused A)
    ushort* tb    = (ushort*)carve((size_t)N * DOUT * 2);  // bf16 fused output
    uint2* ppair  = (uint2*)carve((size_t)NB * CAP * 8);   // bucket scratch 16.8 MB
    int*   psv    = (int*)carve((size_t)NB * CAP * 4);     // bucket scratch 8.4 MB

    hipMemsetAsync(curA, 0, 2 * NB * 4, stream);

    part_kernel<<<NBLK1, 256, 0, stream>>>(src, dst, curA, curB, ppair, psv, E);
    csrn_kernel<<<NB, 512, 0, stream>>>(curA, curB, ppair, psv, csr, rowstart, ndst, nsrc, N, E);

    const int nxb = (N * 32 + 255) / 256;
    prep_kernel<<<nxb + DIN * DHID / 256 + DHID * DOUT / 256, 256, 0, stream>>>(
        x, nsrc, xb, W1, Wt1, W2, Wt2, N);

    // layer 1 aggregation: agg1b = bf16(ndst * segsum(xb[src]))
    aggb_kernel<true, false><<<(N + 15) / 16, 256, 0, stream>>>(xb, csr, rowstart, ndst, nullptr,
                                                                nullptr, agg1b, N);

    // fused GEMM1+GEMM2: tb = bf16( (relu(agg1b @ W1 + b1) * nsrc) @ W2 )
    fused64_kernel<<<(N + 63) / 64, 256, 0, stream>>>(agg1b, Wt1, b1, nsrc, Wt2, tb, N);

    // layer 2 aggregation: out = ndst * segsum(tb[src]) + b2
    aggb_kernel<false, true><<<(N + 15) / 16, 256, 0, stream>>>(tb, csr, rowstart, ndst, b2,
                                                                out, nullptr, N);
}

// Round 9
// 233.462 us; speedup vs baseline: 3.2130x; 1.0284x over previous
//
#include <hip/hip_runtime.h>

constexpr int N_NODES = 100000;
constexpr int N_EDGES = 1600000;
constexpr int DIN = 128, DHID = 256, DOUT = 128;

constexpr int NB = 256;    // buckets
constexpr int BR = 391;    // node range per bucket (256*391 = 100096 >= N)
constexpr int CAP = 8192;  // per-bucket capacity (mean 6250)
constexpr int NBLK1 = 512;
constexpr int CHUNK = (N_EDGES + NBLK1 - 1) / NBLK1;  // 3125

typedef __bf16 bf16x8 __attribute__((ext_vector_type(8)));
typedef float f32x4 __attribute__((ext_vector_type(4)));

static __device__ __forceinline__ ushort f2bf(float f) {
    uint u = __float_as_uint(f);
    uint r = (u + 0x7FFFu + ((u >> 16) & 1u)) >> 16;
    return (ushort)r;
}
static __device__ __forceinline__ float bf2f(ushort h) {
    return __uint_as_float(((uint)h) << 16);
}
static __device__ __forceinline__ float bflo(uint w) { return __uint_as_float(w << 16); }
static __device__ __forceinline__ float bfhi(uint w) { return __uint_as_float(w & 0xFFFF0000u); }

// ---------------- pass 1: partition edges into 256 buckets (single global read, LDS staged) --
// Extra blocks (>= NBLK1) convert W1/W2 to transposed bf16 (independent work, free overlap).
__global__ __launch_bounds__(256) void part_kernel(const int* __restrict__ src,
                                                   const int* __restrict__ dst,
                                                   int* __restrict__ curA, int* __restrict__ curB,
                                                   uint2* __restrict__ ppair,
                                                   int* __restrict__ psv, int e,
                                                   const float* __restrict__ W1,
                                                   ushort* __restrict__ Wt1,
                                                   const float* __restrict__ W2,
                                                   ushort* __restrict__ Wt2) {
    const int t = threadIdx.x;
    if (blockIdx.x >= NBLK1) {  // weight-conversion blocks
        int i = (blockIdx.x - NBLK1) * 256 + t;
        if (i < DIN * DHID) {
            int k = i / DHID, c = i - k * DHID;
            Wt1[(size_t)c * DIN + k] = f2bf(W1[i]);
        } else {
            i -= DIN * DHID;
            int k = i / DOUT, c = i - k * DOUT;
            Wt2[(size_t)c * DHID + k] = f2bf(W2[i]);
        }
        return;
    }
    __shared__ uint2 estage[CHUNK];  // 25 KB
    __shared__ int hA[NB], hB[NB], rA[NB], rB[NB], cA[NB], cB[NB];
    const int b0 = blockIdx.x * CHUNK;
    const int cnt = min(e - b0, CHUNK);
    hA[t] = 0; hB[t] = 0; cA[t] = 0; cB[t] = 0;
    __syncthreads();
    for (int i = t; i < cnt; i += 256) {
        int s = src[b0 + i], d = dst[b0 + i];
        estage[i] = make_uint2((uint)d, (uint)s);
        atomicAdd(&hA[d / BR], 1);
        atomicAdd(&hB[s / BR], 1);
    }
    __syncthreads();
    rA[t] = atomicAdd(&curA[t], hA[t]);  // global reservation (256/block)
    rB[t] = atomicAdd(&curB[t], hB[t]);
    __syncthreads();
    for (int i = t; i < cnt; i += 256) {
        uint2 ed = estage[i];
        int bd = (int)ed.x / BR;
        int bs = (int)ed.y / BR;
        int p = rA[bd] + atomicAdd(&cA[bd], 1);
        if (p < CAP) ppair[(size_t)bd * CAP + p] = ed;
        int q = rB[bs] + atomicAdd(&cB[bs], 1);
        if (q < CAP) psv[(size_t)bs * CAP + q] = (int)ed.y;
    }
}

// ---------------- pass 2: per-bucket CSR + rowstart + ndst + nsrc + xb conversion ------------
__global__ __launch_bounds__(512) void csrn_kernel(const int* __restrict__ curA,
                                                   const int* __restrict__ curB,
                                                   const uint2* __restrict__ ppair,
                                                   const int* __restrict__ psv,
                                                   int* __restrict__ csr,
                                                   int* __restrict__ rowstart,
                                                   float* __restrict__ ndst,
                                                   float* __restrict__ nsrc,
                                                   const float* __restrict__ x,
                                                   ushort* __restrict__ xb, int n, int e) {
    __shared__ ushort dloc[CAP];  // 16KB
    __shared__ uint sloc[CAP];    // 32KB
    __shared__ int hist[512], sc[512], exc[512], cur[512];
    __shared__ int sbst;
    const int t = threadIdx.x;
    const int b = blockIdx.x;
    const int first = b * BR;
    const int nr = min(BR, n - first);
    const int cntA = min(curA[b], CAP);
    const size_t base = (size_t)b * CAP;

    // scan of 256 bucket counts -> this bucket's csr base
    if (t < 256) sc[t] = curA[t];
    __syncthreads();
    for (int off = 1; off < 256; off <<= 1) {
        int add = 0;
        if (t < 256 && t >= off) add = sc[t - off];
        __syncthreads();
        if (t < 256) sc[t] += add;
        __syncthreads();
    }
    if (t == 0) {
        sbst = (b == 0) ? 0 : sc[b - 1];
        if (b == 0) rowstart[n] = e;
    }
    hist[t] = 0;
    cur[t] = 0;
    __syncthreads();
    const int bst = sbst;

    for (int i = t; i < cntA; i += 512) {
        uint2 ed = ppair[base + i];
        int dl = (int)ed.x - first;
        dloc[i] = (ushort)dl;
        sloc[i] = ed.y;
        atomicAdd(&hist[dl], 1);
    }
    __syncthreads();
    int h = hist[t];
    sc[t] = h;
    __syncthreads();
    for (int off = 1; off < 512; off <<= 1) {
        int add = (t >= off) ? sc[t - off] : 0;
        __syncthreads();
        sc[t] += add;
        __syncthreads();
    }
    exc[t] = sc[t] - h;
    if (t < nr) {
        rowstart[first + t] = bst + exc[t];
        ndst[first + t] = rsqrtf(fmaxf((float)h, 1.0f));
    }
    __syncthreads();
    for (int i = t; i < cntA; i += 512) {
        int dl = dloc[i];
        int p = exc[dl] + atomicAdd(&cur[dl], 1);
        csr[bst + p] = (int)sloc[i];
    }

    // out-degree -> nsrc (src-bucketed partition)
    __syncthreads();
    hist[t] = 0;
    __syncthreads();
    const int cntB = min(curB[b], CAP);
    for (int i = t; i < cntB; i += 512) atomicAdd(&hist[psv[base + i] - first], 1);
    __syncthreads();
    float* nsv = (float*)exc;  // exc dead; reuse as float nsrc cache
    if (t < nr) {
        float v = rsqrtf(fmaxf((float)hist[t], 1.0f));
        nsrc[first + t] = v;
        nsv[t] = v;
    }
    __syncthreads();

    // xb = bf16(x * nsrc) for this bucket's nodes: 16 rows x 32 float4-lanes per iter
    const int rl = t >> 5, q = t & 31;
    for (int i = rl; i < nr; i += 16) {
        float s = nsv[i];
        const size_t ro = (size_t)(first + i) * 128;
        float4 v = *(const float4*)&x[ro + q * 4];
        ushort4 o = {f2bf(v.x * s), f2bf(v.y * s), f2bf(v.z * s), f2bf(v.w * s)};
        *(ushort4*)&xb[ro + q * 4] = o;
    }
}

// ---------------- half-feature gather-aggregate: 32 rows/block, 8 lanes x 16B per row --------
// Each dispatch gathers a 128 B half-row -> per-pass line working set 12.8 MB (better L2 hit).
template <bool OUTBF16, bool ADDBIAS>
__global__ __launch_bounds__(256) void aggh_kernel(const ushort* __restrict__ Xb,
                                                   const int* __restrict__ csr,
                                                   const int* __restrict__ rowstart,
                                                   const float* __restrict__ ndst,
                                                   const float* __restrict__ bias,
                                                   float* __restrict__ outf,
                                                   ushort* __restrict__ outb, int n, int half) {
    int g = threadIdx.x >> 3;    // 0..31 row group
    int lane = threadIdx.x & 7;  // 8 lanes x 8 bf16 = 128 B half-row
    int d = blockIdx.x * 32 + g;
    if (d >= n) return;
    int beg = rowstart[d], end = rowstart[d + 1];
    const int fo = half * 64 + lane * 8;
    const ushort* Xp = Xb + fo;
    float acc[8];
#pragma unroll
    for (int j = 0; j < 8; j++) acc[j] = 0.f;

#define ACC8(v)                                   \
    do {                                          \
        acc[0] += bflo(v.x); acc[1] += bfhi(v.x); \
        acc[2] += bflo(v.y); acc[3] += bfhi(v.y); \
        acc[4] += bflo(v.z); acc[5] += bfhi(v.z); \
        acc[6] += bflo(v.w); acc[7] += bfhi(v.w); \
    } while (0)

    int k = beg;
    for (; k + 4 <= end; k += 4) {
        int s0 = csr[k], s1 = csr[k + 1], s2 = csr[k + 2], s3 = csr[k + 3];
        uint4 v0 = *(const uint4*)(Xp + (size_t)s0 * 128);
        uint4 v1 = *(const uint4*)(Xp + (size_t)s1 * 128);
        uint4 v2 = *(const uint4*)(Xp + (size_t)s2 * 128);
        uint4 v3 = *(const uint4*)(Xp + (size_t)s3 * 128);
        ACC8(v0);
        ACC8(v1);
        ACC8(v2);
        ACC8(v3);
    }
    for (; k < end; ++k) {
        uint4 v = *(const uint4*)(Xp + (size_t)csr[k] * 128);
        ACC8(v);
    }
#undef ACC8

    float nd = ndst[d];
#pragma unroll
    for (int j = 0; j < 8; j++) acc[j] *= nd;
    if constexpr (ADDBIAS) {
        float4 b0 = *(const float4*)&bias[fo];
        float4 b1 = *(const float4*)&bias[fo + 4];
        acc[0] += b0.x; acc[1] += b0.y; acc[2] += b0.z; acc[3] += b0.w;
        acc[4] += b1.x; acc[5] += b1.y; acc[6] += b1.z; acc[7] += b1.w;
    }
    if constexpr (OUTBF16) {
        uint4 o;
        o.x = (uint)f2bf(acc[0]) | ((uint)f2bf(acc[1]) << 16);
        o.y = (uint)f2bf(acc[2]) | ((uint)f2bf(acc[3]) << 16);
        o.z = (uint)f2bf(acc[4]) | ((uint)f2bf(acc[5]) << 16);
        o.w = (uint)f2bf(acc[6]) | ((uint)f2bf(acc[7]) << 16);
        *(uint4*)(outb + (size_t)d * 128 + fo) = o;
    } else {
        float4 o0 = {acc[0], acc[1], acc[2], acc[3]};
        float4 o1 = {acc[4], acc[5], acc[6], acc[7]};
        *(float4*)(outf + (size_t)d * 128 + fo) = o0;
        *(float4*)(outf + (size_t)d * 128 + fo + 4) = o1;
    }
}

// ---------------- fused GEMM1+GEMM2, BM=64, weights direct from global ----------------
__global__ __launch_bounds__(256) void fused64_kernel(const ushort* __restrict__ A,
                                                      const ushort* __restrict__ Wt1,
                                                      const float* __restrict__ b1,
                                                      const float* __restrict__ nsrc,
                                                      const ushort* __restrict__ Wt2,
                                                      ushort* __restrict__ T, int M) {
    __shared__ ushort Sa[64][128];  // A tile [m][k], oct' = oct ^ (m&15)   16 KB
    __shared__ ushort H1[64][128];  // H half [m][c], same swizzle          16 KB
    const int row0 = blockIdx.x * 64;
    const int t = threadIdx.x;
    const int w = t >> 6, lane = t & 63;
    const int l16 = lane & 15, lk = lane >> 4;

#pragma unroll
    for (int i = 0; i < 4; i++) {
        int idx = i * 256 + t;  // 1024 uint4 pieces
        int r = idx >> 4, oct = idx & 15;
        int gr = row0 + r;
        uint4 v = make_uint4(0u, 0u, 0u, 0u);
        if (gr < M) v = *(const uint4*)&A[(size_t)gr * 128 + oct * 8];
        *(uint4*)((char*)&Sa[0][0] + r * 256 + (oct ^ (r & 15)) * 16) = v;
    }
    __syncthreads();

    f32x4 acc2[4][2];
#pragma unroll
    for (int i = 0; i < 4; i++)
#pragma unroll
        for (int j = 0; j < 2; j++) acc2[i][j] = (f32x4){0.f, 0.f, 0.f, 0.f};

    for (int kh = 0; kh < 2; kh++) {
        f32x4 acc1[2][4];
#pragma unroll
        for (int i = 0; i < 2; i++)
#pragma unroll
            for (int j = 0; j < 4; j++) acc1[i][j] = (f32x4){0.f, 0.f, 0.f, 0.f};

        bf16x8 af[2][4];  // W1^T fragments, direct from global (prefetched)
#pragma unroll
        for (int i = 0; i < 2; i++)
#pragma unroll
            for (int kb = 0; kb < 4; kb++) {
                int c = w * 32 + i * 16 + l16;
                af[i][kb] =
                    *(const bf16x8*)&Wt1[(size_t)(kh * 128 + c) * 128 + kb * 32 + lk * 8];
            }
#pragma unroll
        for (int kb = 0; kb < 4; kb++) {
            bf16x8 bf_[4];
#pragma unroll
            for (int j = 0; j < 4; j++) {
                int m = j * 16 + l16;
                bf_[j] = *(const bf16x8*)((const char*)&Sa[0][0] + m * 256 +
                                          ((kb * 4 + lk) ^ l16) * 16);
            }
#pragma unroll
            for (int i = 0; i < 2; i++)
#pragma unroll
                for (int j = 0; j < 4; j++)
                    acc1[i][j] =
                        __builtin_amdgcn_mfma_f32_16x16x32_bf16(af[i][kb], bf_[j], acc1[i][j], 0, 0, 0);
        }
        __syncthreads();  // prior phase-D H1 reads done before overwrite

#pragma unroll
        for (int i = 0; i < 2; i++) {
            int cb = w * 32 + i * 16 + lk * 4;
            float4 bv = *(const float4*)&b1[kh * 128 + cb];
#pragma unroll
            for (int j = 0; j < 4; j++) {
                int m = j * 16 + l16;
                int gm = row0 + m;
                float ns = nsrc[gm < M ? gm : (M - 1)];
                ushort4 pk;
                pk.x = f2bf(fmaxf(acc1[i][j][0] + bv.x, 0.f) * ns);
                pk.y = f2bf(fmaxf(acc1[i][j][1] + bv.y, 0.f) * ns);
                pk.z = f2bf(fmaxf(acc1[i][j][2] + bv.z, 0.f) * ns);
                pk.w = f2bf(fmaxf(acc1[i][j][3] + bv.w, 0.f) * ns);
                int oct = cb >> 3;
                *(ushort4*)((char*)&H1[0][0] + m * 256 + ((oct ^ l16) & 15) * 16 +
                            (cb & 7) * 2) = pk;
            }
        }
        __syncthreads();  // H1 visible

        bf16x8 wb[2][4];  // W2 fragments, direct from global (prefetched)
#pragma unroll
        for (int j2 = 0; j2 < 2; j2++)
#pragma unroll
            for (int kb2 = 0; kb2 < 4; kb2++) {
                int c2 = w * 32 + j2 * 16 + l16;
                wb[j2][kb2] =
                    *(const bf16x8*)&Wt2[(size_t)c2 * 256 + kh * 128 + kb2 * 32 + lk * 8];
            }
#pragma unroll
        for (int kb2 = 0; kb2 < 4; kb2++) {
            bf16x8 ha[4];
#pragma unroll
            for (int i2 = 0; i2 < 4; i2++) {
                int m = i2 * 16 + l16;
                ha[i2] = *(const bf16x8*)((const char*)&H1[0][0] + m * 256 +
                                          ((kb2 * 4 + lk) ^ l16) * 16);
            }
#pragma unroll
            for (int i2 = 0; i2 < 4; i2++)
#pragma unroll
                for (int j2 = 0; j2 < 2; j2++)
                    acc2[i2][j2] = __builtin_amdgcn_mfma_f32_16x16x32_bf16(ha[i2], wb[j2][kb2],
                                                                           acc2[i2][j2], 0, 0, 0);
        }
    }

#pragma unroll
    for (int i2 = 0; i2 < 4; i2++) {
#pragma unroll
        for (int j2 = 0; j2 < 2; j2++) {
#pragma unroll
            for (int q = 0; q < 4; q++) {
                int r = row0 + i2 * 16 + lk * 4 + q;
                int c = w * 32 + j2 * 16 + l16;
                if (r < M) T[(size_t)r * DOUT + c] = f2bf(acc2[i2][j2][q]);
            }
        }
    }
}

extern "C" void kernel_launch(void* const* d_in, const int* in_sizes, int n_in,
                              void* d_out, int out_size, void* d_ws, size_t ws_size,
                              hipStream_t stream) {
    const float* x  = (const float*)d_in[0];
    const int*   src = (const int*)d_in[1];
    const int*   dst = (const int*)d_in[2];
    const float* W1 = (const float*)d_in[3];
    const float* b1 = (const float*)d_in[4];
    const float* W2 = (const float*)d_in[5];
    const float* b2 = (const float*)d_in[6];
    float* out = (float*)d_out;

    const int N = N_NODES, E = N_EDGES;

    size_t off = 0;
    auto carve = [&](size_t bytes) -> void* {
        void* p = (char*)d_ws + off;
        off += (bytes + 255) & ~(size_t)255;
        return p;
    };
    int* curA     = (int*)carve(NB * 4);
    int* curB     = (int*)carve(NB * 4);
    int* rowstart = (int*)carve((size_t)(N + 1) * 4);
    float* ndst   = (float*)carve((size_t)N * 4);
    float* nsrc   = (float*)carve((size_t)N * 4);
    int* csr      = (int*)carve((size_t)E * 4);
    ushort* Wt1   = (ushort*)carve(DIN * DHID * 2);
    ushort* Wt2   = (ushort*)carve(DHID * DOUT * 2);
    ushort* xb    = (ushort*)carve((size_t)N * DIN * 2);   // bf16(x*nsrc)
    ushort* agg1b = (ushort*)carve((size_t)N * DIN * 2);   // bf16 aggregate (fused A)
    ushort* tb    = (ushort*)carve((size_t)N * DOUT * 2);  // bf16 fused output
    uint2* ppair  = (uint2*)carve((size_t)NB * CAP * 8);   // bucket scratch 16.8 MB
    int*   psv    = (int*)carve((size_t)NB * CAP * 4);     // bucket scratch 8.4 MB

    hipMemsetAsync(curA, 0, 2 * NB * 4, stream);

    // partition edges + (extra blocks) weight conversion
    part_kernel<<<NBLK1 + 256, 256, 0, stream>>>(src, dst, curA, curB, ppair, psv, E,
                                                 W1, Wt1, W2, Wt2);
    // CSR + norms + xb conversion
    csrn_kernel<<<NB, 512, 0, stream>>>(curA, curB, ppair, psv, csr, rowstart, ndst, nsrc,
                                        x, xb, N, E);

    const int gagg = (N + 31) / 32;
    // layer 1 aggregation (feature-split halves): agg1b = bf16(ndst * segsum(xb[src]))
    aggh_kernel<true, false><<<gagg, 256, 0, stream>>>(xb, csr, rowstart, ndst, nullptr,
                                                       nullptr, agg1b, N, 0);
    aggh_kernel<true, false><<<gagg, 256, 0, stream>>>(xb, csr, rowstart, ndst, nullptr,
                                                       nullptr, agg1b, N, 1);

    // fused GEMM1+GEMM2: tb = bf16( (relu(agg1b @ W1 + b1) * nsrc) @ W2 )
    fused64_kernel<<<(N + 63) / 64, 256, 0, stream>>>(agg1b, Wt1, b1, nsrc, Wt2, tb, N);

    // layer 2 aggregation (feature-split halves): out = ndst * segsum(tb[src]) + b2
    aggh_kernel<false, true><<<gagg, 256, 0, stream>>>(tb, csr, rowstart, ndst, b2,
                                                       out, nullptr, N, 0);
    aggh_kernel<false, true><<<gagg, 256, 0, stream>>>(tb, csr, rowstart, ndst, b2,
                                                       out, nullptr, N, 1);
}

// Round 10
// 217.083 us; speedup vs baseline: 3.4554x; 1.0755x over previous
//
#include <hip/hip_runtime.h>

constexpr int N_NODES = 100000;
constexpr int N_EDGES = 1600000;
constexpr int DIN = 128, DHID = 256, DOUT = 128;

constexpr int NB = 256;    // buckets
constexpr int BR = 391;    // node range per bucket (256*391 = 100096 >= N)
constexpr int CAP = 8192;  // per-bucket capacity (mean 6250)
constexpr int NBLK1 = 512;
constexpr int CHUNK = (N_EDGES + NBLK1 - 1) / NBLK1;  // 3125

typedef __bf16 bf16x8 __attribute__((ext_vector_type(8)));
typedef float f32x4 __attribute__((ext_vector_type(4)));

static __device__ __forceinline__ ushort f2bf(float f) {
    uint u = __float_as_uint(f);
    uint r = (u + 0x7FFFu + ((u >> 16) & 1u)) >> 16;
    return (ushort)r;
}
static __device__ __forceinline__ float bf2f(ushort h) {
    return __uint_as_float(((uint)h) << 16);
}
static __device__ __forceinline__ float bflo(uint w) { return __uint_as_float(w << 16); }
static __device__ __forceinline__ float bfhi(uint w) { return __uint_as_float(w & 0xFFFF0000u); }

// ---------------- pass 1: partition edges into 256 buckets (packed records) ----------------
// ppair entry: (dl << 17) | s   (dl = d - bucket*BR < 512, s < 2^17)
// psv entry:   ushort (s - bucket*BR)
// Extra blocks (>= NBLK1) build PRE-SWIZZLED weight fragment buffers Wf1/Wf2:
//   Wf[frag][lane][e] so a wave's MFMA fragment load is one contiguous 1KB read.
__global__ __launch_bounds__(256) void part_kernel(const int* __restrict__ src,
                                                   const int* __restrict__ dst,
                                                   int* __restrict__ curA, int* __restrict__ curB,
                                                   uint* __restrict__ ppair,
                                                   ushort* __restrict__ psv, int e,
                                                   const float* __restrict__ W1,
                                                   ushort* __restrict__ Wf1,
                                                   const float* __restrict__ W2,
                                                   ushort* __restrict__ Wf2) {
    const int t = threadIdx.x;
    if (blockIdx.x >= NBLK1) {  // weight fragment-layout blocks
        int i = (blockIdx.x - NBLK1) * 256 + t;  // 0..65535
        if (i < DIN * DHID) {
            int frag = i >> 9, r = i & 511;
            int lane = r >> 3, ee = r & 7;
            int kb = frag & 3, ii = (frag >> 2) & 1, w = (frag >> 3) & 3, kh = frag >> 5;
            int c = w * 32 + ii * 16 + (lane & 15);          // W1 col within half
            int k = kb * 32 + (lane >> 4) * 8 + ee;          // W1 row (k-dim)
            Wf1[i] = f2bf(W1[k * DHID + kh * 128 + c]);
        } else {
            int i2 = i - DIN * DHID;
            int frag = i2 >> 9, r = i2 & 511;
            int lane = r >> 3, ee = r & 7;
            int kb2 = frag & 3, j2 = (frag >> 2) & 1, w = (frag >> 3) & 3, kh = frag >> 5;
            int c2 = w * 32 + j2 * 16 + (lane & 15);         // T col
            int k2 = kh * 128 + kb2 * 32 + (lane >> 4) * 8 + ee;  // k-dim in [0,256)
            Wf2[i2] = f2bf(W2[k2 * DOUT + c2]);
        }
        return;
    }
    __shared__ uint2 estage[CHUNK];  // 25 KB
    __shared__ int hA[NB], hB[NB], rA[NB], rB[NB], cA[NB], cB[NB];
    const int b0 = blockIdx.x * CHUNK;
    const int cnt = min(e - b0, CHUNK);
    hA[t] = 0; hB[t] = 0; cA[t] = 0; cB[t] = 0;
    __syncthreads();
    for (int i = t; i < cnt; i += 256) {
        int s = src[b0 + i], d = dst[b0 + i];
        estage[i] = make_uint2((uint)d, (uint)s);
        atomicAdd(&hA[d / BR], 1);
        atomicAdd(&hB[s / BR], 1);
    }
    __syncthreads();
    rA[t] = atomicAdd(&curA[t], hA[t]);  // global reservation (256/block)
    rB[t] = atomicAdd(&curB[t], hB[t]);
    __syncthreads();
    for (int i = t; i < cnt; i += 256) {
        uint2 ed = estage[i];
        int d = (int)ed.x, s = (int)ed.y;
        int bd = d / BR;
        int bs = s / BR;
        int p = rA[bd] + atomicAdd(&cA[bd], 1);
        if (p < CAP) ppair[(size_t)bd * CAP + p] = ((uint)(d - bd * BR) << 17) | (uint)s;
        int q = rB[bs] + atomicAdd(&cB[bs], 1);
        if (q < CAP) psv[(size_t)bs * CAP + q] = (ushort)(s - bs * BR);
    }
}

// ---------------- pass 2: per-bucket CSR + rowstart + ndst + nsrc + xb conversion ------------
__global__ __launch_bounds__(512) void csrn_kernel(const int* __restrict__ curA,
                                                   const int* __restrict__ curB,
                                                   const uint* __restrict__ ppair,
                                                   const ushort* __restrict__ psv,
                                                   int* __restrict__ csr,
                                                   int* __restrict__ rowstart,
                                                   float* __restrict__ ndst,
                                                   float* __restrict__ nsrc,
                                                   const float* __restrict__ x,
                                                   ushort* __restrict__ xb, int n, int e) {
    __shared__ uint ploc[CAP];  // 32KB
    __shared__ int hist[512], sc[512], exc[512], cur[512];
    __shared__ int sbst;
    const int t = threadIdx.x;
    const int b = blockIdx.x;
    const int first = b * BR;
    const int nr = min(BR, n - first);
    const int cntA = min(curA[b], CAP);
    const size_t base = (size_t)b * CAP;

    // scan of 256 bucket counts -> this bucket's csr base
    if (t < 256) sc[t] = curA[t];
    __syncthreads();
    for (int off = 1; off < 256; off <<= 1) {
        int add = 0;
        if (t < 256 && t >= off) add = sc[t - off];
        __syncthreads();
        if (t < 256) sc[t] += add;
        __syncthreads();
    }
    if (t == 0) {
        sbst = (b == 0) ? 0 : sc[b - 1];
        if (b == 0) rowstart[n] = e;
    }
    hist[t] = 0;
    cur[t] = 0;
    __syncthreads();
    const int bst = sbst;

    for (int i = t; i < cntA; i += 512) {
        uint p = ppair[base + i];
        ploc[i] = p;
        atomicAdd(&hist[p >> 17], 1);
    }
    __syncthreads();
    int h = hist[t];
    sc[t] = h;
    __syncthreads();
    for (int off = 1; off < 512; off <<= 1) {
        int add = (t >= off) ? sc[t - off] : 0;
        __syncthreads();
        sc[t] += add;
        __syncthreads();
    }
    exc[t] = sc[t] - h;
    if (t < nr) {
        rowstart[first + t] = bst + exc[t];
        ndst[first + t] = rsqrtf(fmaxf((float)h, 1.0f));
    }
    __syncthreads();
    for (int i = t; i < cntA; i += 512) {
        uint p = ploc[i];
        int dl = p >> 17;
        int pos = exc[dl] + atomicAdd(&cur[dl], 1);
        csr[bst + pos] = (int)(p & 0x1FFFFu);
    }

    // out-degree -> nsrc (src-bucketed partition, local ushort indices)
    __syncthreads();
    hist[t] = 0;
    __syncthreads();
    const int cntB = min(curB[b], CAP);
    for (int i = t; i < cntB; i += 512) atomicAdd(&hist[psv[base + i]], 1);
    __syncthreads();
    float* nsv = (float*)exc;  // exc dead; reuse as float nsrc cache
    if (t < nr) {
        float v = rsqrtf(fmaxf((float)hist[t], 1.0f));
        nsrc[first + t] = v;
        nsv[t] = v;
    }
    __syncthreads();

    // xb = bf16(x * nsrc) for this bucket's nodes: 16 rows x 32 float4-lanes per iter
    const int rl = t >> 5, q = t & 31;
    for (int i = rl; i < nr; i += 16) {
        float s = nsv[i];
        const size_t ro = (size_t)(first + i) * 128;
        float4 v = *(const float4*)&x[ro + q * 4];
        ushort4 o = {f2bf(v.x * s), f2bf(v.y * s), f2bf(v.z * s), f2bf(v.w * s)};
        *(ushort4*)&xb[ro + q * 4] = o;
    }
}

// ---------------- half-feature gather-aggregate: 32 rows/block, 8 lanes x 16B per row --------
template <bool OUTBF16, bool ADDBIAS>
__global__ __launch_bounds__(256) void aggh_kernel(const ushort* __restrict__ Xb,
                                                   const int* __restrict__ csr,
                                                   const int* __restrict__ rowstart,
                                                   const float* __restrict__ ndst,
                                                   const float* __restrict__ bias,
                                                   float* __restrict__ outf,
                                                   ushort* __restrict__ outb, int n, int half) {
    int g = threadIdx.x >> 3;    // 0..31 row group
    int lane = threadIdx.x & 7;  // 8 lanes x 8 bf16 = 128 B half-row
    int d = blockIdx.x * 32 + g;
    if (d >= n) return;
    int beg = rowstart[d], end = rowstart[d + 1];
    const int fo = half * 64 + lane * 8;
    const ushort* Xp = Xb + fo;
    float acc[8];
#pragma unroll
    for (int j = 0; j < 8; j++) acc[j] = 0.f;

#define ACC8(v)                                   \
    do {                                          \
        acc[0] += bflo(v.x); acc[1] += bfhi(v.x); \
        acc[2] += bflo(v.y); acc[3] += bfhi(v.y); \
        acc[4] += bflo(v.z); acc[5] += bfhi(v.z); \
        acc[6] += bflo(v.w); acc[7] += bfhi(v.w); \
    } while (0)

    int k = beg;
    for (; k + 4 <= end; k += 4) {
        int s0 = csr[k], s1 = csr[k + 1], s2 = csr[k + 2], s3 = csr[k + 3];
        uint4 v0 = *(const uint4*)(Xp + (size_t)s0 * 128);
        uint4 v1 = *(const uint4*)(Xp + (size_t)s1 * 128);
        uint4 v2 = *(const uint4*)(Xp + (size_t)s2 * 128);
        uint4 v3 = *(const uint4*)(Xp + (size_t)s3 * 128);
        ACC8(v0);
        ACC8(v1);
        ACC8(v2);
        ACC8(v3);
    }
    for (; k < end; ++k) {
        uint4 v = *(const uint4*)(Xp + (size_t)csr[k] * 128);
        ACC8(v);
    }
#undef ACC8

    float nd = ndst[d];
#pragma unroll
    for (int j = 0; j < 8; j++) acc[j] *= nd;
    if constexpr (ADDBIAS) {
        float4 b0 = *(const float4*)&bias[fo];
        float4 b1 = *(const float4*)&bias[fo + 4];
        acc[0] += b0.x; acc[1] += b0.y; acc[2] += b0.z; acc[3] += b0.w;
        acc[4] += b1.x; acc[5] += b1.y; acc[6] += b1.z; acc[7] += b1.w;
    }
    if constexpr (OUTBF16) {
        uint4 o;
        o.x = (uint)f2bf(acc[0]) | ((uint)f2bf(acc[1]) << 16);
        o.y = (uint)f2bf(acc[2]) | ((uint)f2bf(acc[3]) << 16);
        o.z = (uint)f2bf(acc[4]) | ((uint)f2bf(acc[5]) << 16);
        o.w = (uint)f2bf(acc[6]) | ((uint)f2bf(acc[7]) << 16);
        *(uint4*)(outb + (size_t)d * 128 + fo) = o;
    } else {
        float4 o0 = {acc[0], acc[1], acc[2], acc[3]};
        float4 o1 = {acc[4], acc[5], acc[6], acc[7]};
        *(float4*)(outf + (size_t)d * 128 + fo) = o0;
        *(float4*)(outf + (size_t)d * 128 + fo + 4) = o1;
    }
}

// ---------------- fused GEMM1+GEMM2, BM=64, pre-swizzled weight fragments ----------------
// Weights load as wave-contiguous 1KB fragments; all 16 frag loads for a kh issued at kh-top
// (wb latency hides under phase B + epilogue). nsrc/bias prefetched before the stage barrier.
__global__ __launch_bounds__(256) void fused64_kernel(const ushort* __restrict__ A,
                                                      const ushort* __restrict__ Wf1,
                                                      const float* __restrict__ b1,
                                                      const float* __restrict__ nsrc,
                                                      const ushort* __restrict__ Wf2,
                                                      ushort* __restrict__ T, int M) {
    __shared__ ushort Sa[64][128];  // A tile [m][k], oct' = oct ^ (m&15)   16 KB
    __shared__ ushort H1[64][128];  // H half [m][c], same swizzle          16 KB
    const int row0 = blockIdx.x * 64;
    const int t = threadIdx.x;
    const int w = t >> 6, lane = t & 63;
    const int l16 = lane & 15, lk = lane >> 4;

    // prefetch per-lane nsrc + biases (tiny, before barrier)
    float nsv[4];
#pragma unroll
    for (int j = 0; j < 4; j++) {
        int gm = row0 + j * 16 + l16;
        nsv[j] = nsrc[gm < M ? gm : (M - 1)];
    }
    float4 bvv[2][2];
#pragma unroll
    for (int kh = 0; kh < 2; kh++)
#pragma unroll
        for (int i = 0; i < 2; i++)
            bvv[kh][i] = *(const float4*)&b1[kh * 128 + w * 32 + i * 16 + lk * 4];

    // stage A tile once (64 rows x 128 k)
#pragma unroll
    for (int i = 0; i < 4; i++) {
        int idx = i * 256 + t;  // 1024 uint4 pieces
        int r = idx >> 4, oct = idx & 15;
        int gr = row0 + r;
        uint4 v = make_uint4(0u, 0u, 0u, 0u);
        if (gr < M) v = *(const uint4*)&A[(size_t)gr * 128 + oct * 8];
        *(uint4*)((char*)&Sa[0][0] + r * 256 + (oct ^ (r & 15)) * 16) = v;
    }
    __syncthreads();

    f32x4 acc2[4][2];
#pragma unroll
    for (int i = 0; i < 4; i++)
#pragma unroll
        for (int j = 0; j < 2; j++) acc2[i][j] = (f32x4){0.f, 0.f, 0.f, 0.f};

    for (int kh = 0; kh < 2; kh++) {
        // ---- all 16 weight fragment loads for this kh, coalesced 1KB each ----
        const ushort* w1p = Wf1 + ((size_t)(kh * 4 + w) * 8) * 512 + lane * 8;
        const ushort* w2p = Wf2 + ((size_t)(kh * 4 + w) * 8) * 512 + lane * 8;
        bf16x8 af[2][4], wb[2][4];
#pragma unroll
        for (int i = 0; i < 2; i++)
#pragma unroll
            for (int kb = 0; kb < 4; kb++) af[i][kb] = *(const bf16x8*)(w1p + (i * 4 + kb) * 512);
#pragma unroll
        for (int j2 = 0; j2 < 2; j2++)
#pragma unroll
            for (int kb2 = 0; kb2 < 4; kb2++)
                wb[j2][kb2] = *(const bf16x8*)(w2p + (j2 * 4 + kb2) * 512);

        // ---- phase B: acc1 = (A @ W1half)^T ; wave w owns c-rows [w*32, w*32+32) ----
        f32x4 acc1[2][4];
#pragma unroll
        for (int i = 0; i < 2; i++)
#pragma unroll
            for (int j = 0; j < 4; j++) acc1[i][j] = (f32x4){0.f, 0.f, 0.f, 0.f};

#pragma unroll
        for (int kb = 0; kb < 4; kb++) {
            bf16x8 bf_[4];
#pragma unroll
            for (int j = 0; j < 4; j++) {
                int m = j * 16 + l16;
                bf_[j] = *(const bf16x8*)((const char*)&Sa[0][0] + m * 256 +
                                          ((kb * 4 + lk) ^ l16) * 16);
            }
#pragma unroll
            for (int i = 0; i < 2; i++)
#pragma unroll
                for (int j = 0; j < 4; j++)
                    acc1[i][j] =
                        __builtin_amdgcn_mfma_f32_16x16x32_bf16(af[i][kb], bf_[j], acc1[i][j], 0, 0, 0);
        }
        __syncthreads();  // prior phase-D H1 reads done before overwrite

        // ---- epilogue: lane holds D[c = w*32+i*16+lk*4+q][m = j*16+l16] -> H1 ----
#pragma unroll
        for (int i = 0; i < 2; i++) {
            int cb = w * 32 + i * 16 + lk * 4;
            float4 bv = bvv[kh][i];
#pragma unroll
            for (int j = 0; j < 4; j++) {
                int m = j * 16 + l16;
                float ns = nsv[j];
                ushort4 pk;
                pk.x = f2bf(fmaxf(acc1[i][j][0] + bv.x, 0.f) * ns);
                pk.y = f2bf(fmaxf(acc1[i][j][1] + bv.y, 0.f) * ns);
                pk.z = f2bf(fmaxf(acc1[i][j][2] + bv.z, 0.f) * ns);
                pk.w = f2bf(fmaxf(acc1[i][j][3] + bv.w, 0.f) * ns);
                int oct = cb >> 3;
                *(ushort4*)((char*)&H1[0][0] + m * 256 + ((oct ^ l16) & 15) * 16 +
                            (cb & 7) * 2) = pk;
            }
        }
        __syncthreads();  // H1 visible

        // ---- phase D: acc2 += H1 @ W2half ; wave w owns T-cols [w*32, w*32+32) ----
#pragma unroll
        for (int kb2 = 0; kb2 < 4; kb2++) {
            bf16x8 ha[4];
#pragma unroll
            for (int i2 = 0; i2 < 4; i2++) {
                int m = i2 * 16 + l16;
                ha[i2] = *(const bf16x8*)((const char*)&H1[0][0] + m * 256 +
                                          ((kb2 * 4 + lk) ^ l16) * 16);
            }
#pragma unroll
            for (int i2 = 0; i2 < 4; i2++)
#pragma unroll
                for (int j2 = 0; j2 < 2; j2++)
                    acc2[i2][j2] = __builtin_amdgcn_mfma_f32_16x16x32_bf16(ha[i2], wb[j2][kb2],
                                                                           acc2[i2][j2], 0, 0, 0);
        }
    }

    // ---- write T: C/D layout col=lane&15, row=(lane>>4)*4+q ----
#pragma unroll
    for (int i2 = 0; i2 < 4; i2++) {
#pragma unroll
        for (int j2 = 0; j2 < 2; j2++) {
#pragma unroll
            for (int q = 0; q < 4; q++) {
                int r = row0 + i2 * 16 + lk * 4 + q;
                int c = w * 32 + j2 * 16 + l16;
                if (r < M) T[(size_t)r * DOUT + c] = f2bf(acc2[i2][j2][q]);
            }
        }
    }
}

extern "C" void kernel_launch(void* const* d_in, const int* in_sizes, int n_in,
                              void* d_out, int out_size, void* d_ws, size_t ws_size,
                              hipStream_t stream) {
    const float* x  = (const float*)d_in[0];
    const int*   src = (const int*)d_in[1];
    const int*   dst = (const int*)d_in[2];
    const float* W1 = (const float*)d_in[3];
    const float* b1 = (const float*)d_in[4];
    const float* W2 = (const float*)d_in[5];
    const float* b2 = (const float*)d_in[6];
    float* out = (float*)d_out;

    const int N = N_NODES, E = N_EDGES;

    size_t off = 0;
    auto carve = [&](size_t bytes) -> void* {
        void* p = (char*)d_ws + off;
        off += (bytes + 255) & ~(size_t)255;
        return p;
    };
    int* curA     = (int*)carve(NB * 4);
    int* curB     = (int*)carve(NB * 4);
    int* rowstart = (int*)carve((size_t)(N + 1) * 4);
    float* ndst   = (float*)carve((size_t)N * 4);
    float* nsrc   = (float*)carve((size_t)N * 4);
    int* csr      = (int*)carve((size_t)E * 4);
    ushort* Wf1   = (ushort*)carve(DIN * DHID * 2);        // fragment-ordered
    ushort* Wf2   = (ushort*)carve(DHID * DOUT * 2);       // fragment-ordered
    ushort* xb    = (ushort*)carve((size_t)N * DIN * 2);   // bf16(x*nsrc)
    ushort* agg1b = (ushort*)carve((size_t)N * DIN * 2);   // bf16 aggregate (fused A)
    ushort* tb    = (ushort*)carve((size_t)N * DOUT * 2);  // bf16 fused output
    uint*   ppair = (uint*)carve((size_t)NB * CAP * 4);    // packed (dl<<17 | s)  8.4 MB
    ushort* psv   = (ushort*)carve((size_t)NB * CAP * 2);  // packed local src     4.2 MB

    hipMemsetAsync(curA, 0, 2 * NB * 4, stream);

    // partition edges + (extra blocks) weight fragment layout
    part_kernel<<<NBLK1 + 256, 256, 0, stream>>>(src, dst, curA, curB, ppair, psv, E,
                                                 W1, Wf1, W2, Wf2);
    // CSR + norms + xb conversion
    csrn_kernel<<<NB, 512, 0, stream>>>(curA, curB, ppair, psv, csr, rowstart, ndst, nsrc,
                                        x, xb, N, E);

    const int gagg = (N + 31) / 32;
    // layer 1 aggregation (feature-split halves): agg1b = bf16(ndst * segsum(xb[src]))
    aggh_kernel<true, false><<<gagg, 256, 0, stream>>>(xb, csr, rowstart, ndst, nullptr,
                                                       nullptr, agg1b, N, 0);
    aggh_kernel<true, false><<<gagg, 256, 0, stream>>>(xb, csr, rowstart, ndst, nullptr,
                                                       nullptr, agg1b, N, 1);

    // fused GEMM1+GEMM2: tb = bf16( (relu(agg1b @ W1 + b1) * nsrc) @ W2 )
    fused64_kernel<<<(N + 63) / 64, 256, 0, stream>>>(agg1b, Wf1, b1, nsrc, Wf2, tb, N);

    // layer 2 aggregation (feature-split halves): out = ndst * segsum(tb[src]) + b2
    aggh_kernel<false, true><<<gagg, 256, 0, stream>>>(tb, csr, rowstart, ndst, b2,
                                                       out, nullptr, N, 0);
    aggh_kernel<false, true><<<gagg, 256, 0, stream>>>(tb, csr, rowstart, ndst, b2,
                                                       out, nullptr, N, 1);
}